// Round 1
// baseline (148479.236 us; speedup 1.0000x reference)
//
#include <hip/hip_runtime.h>
#include <hip/hip_cooperative_groups.h>

namespace cg = cooperative_groups;

#define NB 256      // grid blocks
#define BT 256      // threads per block

#define BB 64       // batch
#define TT 1024     // encoder time
#define LL 400      // decoder steps
#define EE 512      // enc dim
#define DD 80       // dec dim
#define AA 512      // attn/GRU dim
#define KK 5        // mixture components

struct Pr {
  const float *enc;
  const float *pW1, *pb1, *pW2, *pb2;
  const float *gWx, *gWh, *gbx, *gbh;
  const float *aW1, *ab1, *aW2, *ab2;
  const float *lWx1, *lWh1, *lb1, *lWx2, *lWh2, *lb2;
  const float *sW, *sb;
  float *oa, *obf, *ol;                    // outputs: after, before, logits
  float *ha, *means, *h1, *c1, *h2, *c2, *p, *q, *ctx; // ws state
};

__device__ __forceinline__ float sigm(float x){ return 1.f/(1.f+expf(-x)); }
__device__ __forceinline__ float softplusf(float x){ return fmaxf(x,0.f)+log1pf(expf(-fabsf(x))); }

#define SM_SIZE 1600
// Phase LDS maps (floats):
//  P1/P2/P5: gate partials [0..256)
//  P4: attn_w row [0..1024), param red [1024..1264), prm [1264..1279),
//      mu [1280..1285), sc [1285..1290), mw [1290..1295), ctx red [1300..1556)
//  P6: h1s [0..80), h2s [80..160), gates [160..480), h2n [480..560),
//      logit red [560..640), prenet hidden [640..720)

// prenet from sm[480..560) (h2 vector) -> P_.p[b*DD ..)
__device__ __forceinline__ void prenet_from_h2n(const Pr& P_, float* sm, int b, int tid){
  if (tid < DD){
    float s = P_.pb1[tid];
    #pragma unroll 8
    for (int i=0;i<DD;i++) s += sm[480+i]*P_.pW1[i*DD+tid];
    sm[640+tid] = fmaxf(s, 0.f);
  }
  __syncthreads();
  if (tid < DD){
    float s = P_.pb2[tid];
    #pragma unroll 8
    for (int i=0;i<DD;i++) s += sm[640+i]*P_.pW2[i*DD+tid];
    P_.p[b*DD+tid] = fmaxf(s, 0.f);
  }
}

__global__ __launch_bounds__(BT) void decoder_kernel(Pr P_){
  cg::grid_group grid = cg::this_grid();
  const int blk = blockIdx.x, tid = threadIdx.x;
  __shared__ float sm[SM_SIZE];
  __shared__ int itlo, ithi;

  // ---- init: zero all recurrent state (ha..p contiguous from ws base) ----
  for (int i = blk*BT+tid; i < 97280; i += NB*BT) P_.ha[i] = 0.f;
  grid.sync();
  if (blk < BB){
    if (tid < DD) sm[480+tid] = 0.f;   // h2 = 0
    __syncthreads();
    prenet_from_h2n(P_, sm, blk, tid); // p for step 0
  }
  grid.sync();

  for (int l=0; l<LL; ++l){
    const float* hin   = P_.ha    + (l&1)*(BB*AA);
    float*       hout  = P_.ha    + ((l+1)&1)*(BB*AA);
    const float* h1in  = P_.h1    + (l&1)*(BB*DD);
    float*       h1out = P_.h1    + ((l+1)&1)*(BB*DD);
    const float* mnsi  = P_.means + (l&1)*(BB*8);
    float*       mnso  = P_.means + ((l+1)&1)*(BB*8);

    // ================= P1: GRU (units 2*blk, 2*blk+1; roles r|z|xn|hn) =====
    {
      const int b = tid & 63, role = tid >> 6;
      for (int ui=0; ui<2; ++ui){
        const int u = blk*2 + ui;
        float s;
        if (role <= 1){                    // combined xr+hr / xz+hz
          const int c = role*AA + u;
          s = P_.gbx[c] + P_.gbh[c];
          const float* ph = P_.p + b*DD;
          const float* wx = P_.gWx + c;
          #pragma unroll 4
          for (int i=0;i<DD;i++) s += ph[i]*wx[i*(3*AA)];
          const float* hh = hin + b*AA;
          const float* wh = P_.gWh + c;
          #pragma unroll 4
          for (int j=0;j<AA;j++) s += hh[j]*wh[j*(3*AA)];
        } else if (role == 2){             // xn
          const int c = 2*AA + u;
          s = P_.gbx[c];
          const float* ph = P_.p + b*DD;
          const float* wx = P_.gWx + c;
          #pragma unroll 4
          for (int i=0;i<DD;i++) s += ph[i]*wx[i*(3*AA)];
        } else {                           // hn
          const int c = 2*AA + u;
          s = P_.gbh[c];
          const float* hh = hin + b*AA;
          const float* wh = P_.gWh + c;
          #pragma unroll 4
          for (int j=0;j<AA;j++) s += hh[j]*wh[j*(3*AA)];
        }
        sm[role*64+b] = s;
        __syncthreads();
        if (tid < 64){
          float r = sigm(sm[tid]);
          float z = sigm(sm[64+tid]);
          float n = tanhf(sm[128+tid] + r*sm[192+tid]);
          hout[tid*AA+u] = (1.f-z)*n + z*hin[tid*AA+u];
        }
        __syncthreads();
      }
    }
    grid.sync();

    // ================= P2: q = tanh(h_att @ att_W1 + b1) ===================
    {
      const int b = tid & 63, ch = tid >> 6;
      for (int ci=0; ci<2; ++ci){
        const int col = blk*2+ci;
        const float* hh = hout + b*AA + ch*128;
        const float* w  = P_.aW1 + ch*128*AA + col;
        float s = 0.f;
        #pragma unroll 4
        for (int i=0;i<128;i++) s += hh[i]*w[i*AA];
        sm[ch*64+b] = s;
        __syncthreads();
        if (tid < 64)
          P_.q[tid*AA+col] = tanhf(sm[tid]+sm[64+tid]+sm[128+tid]+sm[192+tid] + P_.ab1[col]);
        __syncthreads();
      }
    }
    grid.sync();

    // ====== P4: mixture params + attn weights + context (blk = b*4+etile) ==
    {
      const int b = blk >> 2, et = blk & 3;
      if (tid < 240){                       // params = q @ W2 (+b2): 15 cols x 16 chunks
        const int col = tid >> 4, ch = tid & 15;
        const float* qb = P_.q + b*AA + ch*32;
        const float* w  = P_.aW2 + ch*32*(3*KK) + col;
        float s=0.f;
        #pragma unroll 4
        for (int i=0;i<32;i++) s += qb[i]*w[i*(3*KK)];
        sm[1024 + col*16 + ch] = s;
      }
      __syncthreads();
      if (tid < 15){
        float s = P_.ab2[tid];
        #pragma unroll
        for (int i=0;i<16;i++) s += sm[1024+tid*16+i];
        sm[1264+tid] = s;
      }
      __syncthreads();
      if (tid == 0){
        float lo = 3.4e38f, hi = -3.4e38f, mmax = -3.4e38f;
        for (int k=0;k<KK;k++){
          float m  = mnsi[b*8+k] + softplusf(sm[1264+k]);
          sm[1280+k] = m;
          if (et == 0) mnso[b*8+k] = m;     // single writer; others read old buffer
          float sc = softplusf(sm[1264+5+k]) + 1e-4f;
          sm[1285+k] = sc;
          mmax = fmaxf(mmax, sm[1264+10+k]);
          lo = fminf(lo, m - 0.5f - 26.f*sc);  // e^-26 tail: skipped mass < 1e-11
          hi = fmaxf(hi, m + 0.5f + 26.f*sc);
        }
        float den = 0.f;
        for (int k=0;k<KK;k++){ float e = expf(sm[1264+10+k]-mmax); sm[1290+k]=e; den += e; }
        float rd = 1.f/den;
        for (int k=0;k<KK;k++) sm[1290+k] *= rd;
        int ilo = (int)fmaxf(0.f, floorf(lo));
        int ihi = (int)fminf((float)TT, ceilf(hi)+1.f);
        if (ihi < ilo) ihi = ilo;
        itlo = ilo; ithi = ihi;
      }
      __syncthreads();
      const int tlo = itlo, thi = ithi;
      for (int t = tlo + tid; t < thi; t += BT){   // attn weights into LDS
        float aw = 0.f;
        #pragma unroll
        for (int k=0;k<KK;k++){
          float mu = sm[1280+k], sc = sm[1285+k];
          float zh = ((float)t + 0.5f - mu)/sc;
          float zl = ((float)t - 0.5f - mu)/sc;
          aw += sm[1290+k]*(sigm(zh)-sigm(zl));
        }
        sm[t] = aw;
      }
      __syncthreads();
      const int e0 = et*128 + (tid & 127);         // context over window
      const int half = tid >> 7;
      const float* zb = P_.enc + (size_t)b*(TT*EE) + e0;
      float acc = 0.f;
      for (int t = tlo + half; t < thi; t += 2)
        acc += sm[t]*zb[(size_t)t*EE];
      sm[1300 + half*128 + (tid&127)] = acc;
      __syncthreads();
      if (tid < 128)
        P_.ctx[b*EE + et*128 + tid] = sm[1300+tid] + sm[1428+tid];
    }
    grid.sync();

    // ================= P5: LSTM layer 1 (block = unit u) ===================
    if (blk < DD){
      const int u = blk;
      const int b = tid & 63, g = tid >> 6;
      const int col = g*DD + u;
      float s = P_.lb1[col];
      const float* cb  = P_.ctx + b*EE;
      const float* hb  = hout + b*AA;
      const float* w   = P_.lWx1 + col;
      #pragma unroll 4
      for (int i=0;i<EE;i++) s += cb[i]*w[i*(4*DD)];
      #pragma unroll 4
      for (int i=0;i<AA;i++) s += hb[i]*w[(EE+i)*(4*DD)];
      const float* h1b = h1in + b*DD;
      const float* wh  = P_.lWh1 + col;
      #pragma unroll 4
      for (int i=0;i<DD;i++) s += h1b[i]*wh[i*(4*DD)];
      sm[g*64+b] = s;
      __syncthreads();
      if (tid < 64){
        float i_ = sigm(sm[tid]);
        float f_ = sigm(sm[64+tid]);
        float g_ = tanhf(sm[128+tid]);
        float o_ = sigm(sm[192+tid]);
        float cn = f_*P_.c1[tid*DD+u] + i_*g_;
        P_.c1[tid*DD+u] = cn;
        h1out[tid*DD+u] = o_*tanhf(cn);
      }
    }
    grid.sync();

    // ============ P6: LSTM layer 2 + outputs + prenet for next step ========
    if (blk < BB){
      const int b = blk;
      if (tid < DD) sm[tid] = h1out[b*DD+tid];
      else if (tid >= 128 && tid < 128+DD) sm[80 + tid-128] = P_.h2[b*DD + tid-128];
      __syncthreads();
      for (int col = tid; col < 4*DD; col += BT){
        float s = P_.lb2[col];
        #pragma unroll 4
        for (int i=0;i<DD;i++) s += sm[i]   *P_.lWx2[i*(4*DD)+col];
        #pragma unroll 4
        for (int i=0;i<DD;i++) s += sm[80+i]*P_.lWh2[i*(4*DD)+col];
        sm[160+col] = s;
      }
      __syncthreads();
      if (tid < DD){
        float i_ = sigm(sm[160+tid]);
        float f_ = sigm(sm[160+DD+tid]);
        float g_ = tanhf(sm[160+2*DD+tid]);
        float o_ = sigm(sm[160+3*DD+tid]);
        float cn = f_*P_.c2[b*DD+tid] + i_*g_;
        P_.c2[b*DD+tid] = cn;
        float hn = o_*tanhf(cn);
        sm[480+tid] = hn;
        P_.h2[b*DD+tid] = hn;
        const size_t oidx = (size_t)(b*LL + l)*DD + tid;
        P_.oa[oidx]  = hn;
        P_.obf[oidx] = hn;
      }
      __syncthreads();
      if (tid < DD) sm[560+tid] = sm[480+tid]*P_.sW[tid];
      __syncthreads();
      if (tid == 0){
        float s = P_.sb[0];
        for (int i=0;i<DD;i++) s += sm[560+i];
        P_.ol[b*LL + l] = s;
      }
      __syncthreads();
      prenet_from_h2n(P_, sm, b, tid);
    }
    grid.sync();
  }
}

extern "C" void kernel_launch(void* const* d_in, const int* in_sizes, int n_in,
                              void* d_out, int out_size, void* d_ws, size_t ws_size,
                              hipStream_t stream){
  (void)in_sizes; (void)n_in; (void)out_size;
  if (ws_size < (size_t)162816*sizeof(float)) return;

  Pr P_;
  P_.enc = (const float*)d_in[0];
  // d_in[1] = ys (teacher inputs) is unused by the reference (free-running feedback)
  P_.pW1=(const float*)d_in[2];  P_.pb1=(const float*)d_in[3];
  P_.pW2=(const float*)d_in[4];  P_.pb2=(const float*)d_in[5];
  P_.gWx=(const float*)d_in[6];  P_.gWh=(const float*)d_in[7];
  P_.gbx=(const float*)d_in[8];  P_.gbh=(const float*)d_in[9];
  P_.aW1=(const float*)d_in[10]; P_.ab1=(const float*)d_in[11];
  P_.aW2=(const float*)d_in[12]; P_.ab2=(const float*)d_in[13];
  P_.lWx1=(const float*)d_in[14]; P_.lWh1=(const float*)d_in[15]; P_.lb1=(const float*)d_in[16];
  P_.lWx2=(const float*)d_in[17]; P_.lWh2=(const float*)d_in[18]; P_.lb2=(const float*)d_in[19];
  P_.sW=(const float*)d_in[20];  P_.sb=(const float*)d_in[21];

  float* ws = (float*)d_ws;
  P_.ha    = ws;           // 2 x 64x512
  P_.means = ws + 65536;   // 2 x 64x8
  P_.h1    = ws + 66560;   // 2 x 64x80
  P_.c1    = ws + 76800;   // 64x80
  P_.h2    = ws + 81920;   // 64x80
  P_.c2    = ws + 87040;   // 64x80
  P_.p     = ws + 92160;   // 64x80
  P_.q     = ws + 97280;   // 64x512
  P_.ctx   = ws + 130048;  // 64x512

  float* o = (float*)d_out;
  P_.oa  = o;                         // after  [B,L,D]
  P_.obf = o + (size_t)BB*LL*DD;      // before [B,L,D]
  P_.ol  = o + (size_t)2*BB*LL*DD;    // logits [B,L]

  void* args[] = { (void*)&P_ };
  hipLaunchCooperativeKernel((void*)decoder_kernel, dim3(NB), dim3(BT), args, 0, stream);
}

// Round 3
// 122405.786 us; speedup vs baseline: 1.2130x; 1.2130x over previous
//
#include <hip/hip_runtime.h>
#include <hip/hip_cooperative_groups.h>

namespace cg = cooperative_groups;

#define NB 256      // grid blocks (1 per CU — cooperative co-residency guaranteed)
#define BT 512      // threads per block (8 waves/CU)

#define BB 64       // batch
#define TT 1024     // encoder time
#define LL 400      // decoder steps
#define EE 512      // enc dim
#define DD 80       // dec dim
#define AA 512      // attn/GRU dim
#define KK 5        // mixture components

struct Pr {
  const float *enc;
  const float *pW1, *pb1, *pW2, *pb2;
  const float *gWx, *gWh, *gbx, *gbh;
  const float *aW1, *ab1, *aW2, *ab2;
  const float *lWx1, *lWh1, *lb1, *lWx2, *lWh2, *lb2;
  const float *sW, *sb;
  float *oa, *obf, *ol;
  float *ha, *means, *h1, *c1, *h2, *c2, *p, *q, *ctx;
};

__device__ __forceinline__ float sigm(float x){ return 1.f/(1.f+expf(-x)); }
__device__ __forceinline__ float softplusf(float x){ return fmaxf(x,0.f)+log1pf(expf(-fabsf(x))); }

// LDS (floats):
//  P1: h-stage [0..4128) stride 516, p-stage [4128..4800) stride 84, red [4800..6848)
//  P2: h-stage [0..4128), red [4800..5312)
//  P4: aw [0..1024), pchunk [1024..1264), prm [1264..1295), ctxred [1300..1812)
//  P5: x-stage [0..8864) stride 1108, red [8864..9376)
//  P6: h1 [0..80), h2 [80..160), gates [160..480), h2n [480..560), stop [560..640), ph [640..720)
#define SM_SIZE 9600

__global__ __launch_bounds__(BT, 2) void decoder_kernel(Pr P_){
  cg::grid_group grid = cg::this_grid();
  const int blk = blockIdx.x, tid = threadIdx.x;
  __shared__ float sm[SM_SIZE];
  __shared__ int itlo, ithi;

  const int a8  = blk & 7;          // xcd slot
  const int bg8 = (blk >> 3) & 7;   // batch group (8 batches)
  const int cgl = blk >> 6;         // 0..3
  const int b0  = bg8 * 8;

  // ---- init: zero recurrent state (ha..p contiguous = 97280 floats) ----
  for (int i = blk*BT+tid; i < 97280; i += NB*BT) P_.ha[i] = 0.f;
  grid.sync();
  if (blk < BB){   // p0 = prenet(0)
    if (tid < DD) sm[640+tid] = fmaxf(P_.pb1[tid], 0.f);
    __syncthreads();
    if (tid < DD){
      float s = P_.pb2[tid];
      for (int i=0;i<DD;i++) s += sm[640+i]*P_.pW2[i*DD+tid];
      P_.p[blk*DD+tid] = fmaxf(s, 0.f);
    }
  }
  grid.sync();

  for (int l=0; l<LL; ++l){
    const float* hin   = P_.ha    + (l&1)*(BB*AA);
    float*       hout  = P_.ha    + ((l+1)&1)*(BB*AA);
    const float* h1in  = P_.h1    + (l&1)*(BB*DD);
    float*       h1out = P_.h1    + ((l+1)&1)*(BB*DD);
    const float* mnsi  = P_.means + (l&1)*(BB*8);
    float*       mnso  = P_.means + ((l+1)&1)*(BB*8);

    // ========== P1: GRU. block covers 2 unit-groups of 8 units x 8 batches ==========
    {
      for (int idx = tid; idx < 1024; idx += BT){        // stage hin rows
        int r = idx >> 7, q4 = idx & 127;
        *(float4*)&sm[r*516 + 4*q4] = *(const float4*)&hin[(b0+r)*AA + 4*q4];
      }
      for (int idx = tid; idx < 160; idx += BT){         // stage p rows
        int r = idx/20, q4 = idx%20;
        *(float4*)&sm[4128 + r*84 + 4*q4] = *(const float4*)&P_.p[(b0+r)*DD + 4*q4];
      }
      __syncthreads();
      for (int g2=0; g2<2; ++g2){
        const int ug = a8 + 8*(2*cgl + g2);   // 0..63
        const int u0 = ug*8;
        const int u_ = tid & 7, bl = (tid>>3)&7, jh = tid>>6;  // jh 0..7
        const int col = u0 + u_;
        float ar=0.f, az=0.f, axn=0.f, ahn=0.f;
        if (jh < 4){ // p-part: 20 j per quarter
          const float* ps = &sm[4128 + bl*84 + jh*20];
          const float* W  = P_.gWx + col + (jh*20)*1536;
          #pragma unroll 5
          for (int j4=0;j4<5;++j4){
            float4 v = *(const float4*)(ps + 4*j4);
            ar += v.x*W[0];    az += v.x*W[512];   axn += v.x*W[1024];
            ar += v.y*W[1536]; az += v.y*W[2048];  axn += v.y*W[2560];
            ar += v.z*W[3072]; az += v.z*W[3584];  axn += v.z*W[4096];
            ar += v.w*W[4608]; az += v.w*W[5120];  axn += v.w*W[5632];
            W += 6144;
          }
        }
        { // h-part: 64 j per eighth
          const float* hs = &sm[bl*516 + jh*64];
          const float* W  = P_.gWh + col + (jh*64)*1536;
          #pragma unroll 4
          for (int j4=0;j4<16;++j4){
            float4 v = *(const float4*)(hs + 4*j4);
            ar += v.x*W[0];    az += v.x*W[512];   ahn += v.x*W[1024];
            ar += v.y*W[1536]; az += v.y*W[2048];  ahn += v.y*W[2560];
            ar += v.z*W[3072]; az += v.z*W[3584];  ahn += v.z*W[4096];
            ar += v.w*W[4608]; az += v.w*W[5120];  ahn += v.w*W[5632];
            W += 6144;
          }
        }
        float* red = &sm[4800];
        red[tid*4+0]=ar; red[tid*4+1]=az; red[tid*4+2]=axn; red[tid*4+3]=ahn;
        __syncthreads();
        if (tid < 64){
          float r_=0,z_=0,xn=0,hn=0;
          #pragma unroll
          for (int q=0;q<8;q++){
            const float* rr = &red[(tid + 64*q)*4];
            r_+=rr[0]; z_+=rr[1]; xn+=rr[2]; hn+=rr[3];
          }
          const int uu = u0 + (tid&7), bb = b0 + (tid>>3);
          float r = sigm(r_ + P_.gbx[uu] + P_.gbh[uu]);
          float z = sigm(z_ + P_.gbx[512+uu] + P_.gbh[512+uu]);
          float n = tanhf(xn + P_.gbx[1024+uu] + r*(hn + P_.gbh[1024+uu]));
          float hprev = sm[(tid>>3)*516 + uu];
          hout[bb*AA + uu] = (1.f-z)*n + z*hprev;
        }
        __syncthreads();
      }
    }
    grid.sync();

    // ========== P2: q = tanh(hout @ aW1 + b1). 2 col-groups of 8 x 8 batches ==========
    {
      for (int idx = tid; idx < 1024; idx += BT){
        int r = idx >> 7, q4 = idx & 127;
        *(float4*)&sm[r*516 + 4*q4] = *(const float4*)&hout[(b0+r)*AA + 4*q4];
      }
      __syncthreads();
      for (int g2=0; g2<2; ++g2){
        const int c0 = (a8 + 8*(2*cgl + g2))*8;
        const int c_ = tid & 7, bl = (tid>>3)&7, jh = tid>>6;
        const int col = c0 + c_;
        float a0=0,a1=0,a2=0,a3=0;
        const float* hs = &sm[bl*516 + jh*64];
        const float* W  = P_.aW1 + col + (jh*64)*512;
        #pragma unroll 4
        for (int j4=0;j4<16;++j4){
          float4 v = *(const float4*)(hs + 4*j4);
          a0 += v.x*W[0]; a1 += v.y*W[512]; a2 += v.z*W[1024]; a3 += v.w*W[1536];
          W += 2048;
        }
        sm[4800+tid] = (a0+a1)+(a2+a3);
        __syncthreads();
        if (tid < 64){
          float s = 0.f;
          #pragma unroll
          for (int q=0;q<8;q++) s += sm[4800 + tid + 64*q];
          P_.q[(b0+(tid>>3))*AA + c0+(tid&7)] = tanhf(s + P_.ab1[c0+(tid&7)]);
        }
        __syncthreads();
      }
    }
    grid.sync();

    // ========== P4: params + attn + ctx. block = b*4 + etile ==========
    {
      const int b = blk >> 2, et = blk & 3;
      if (tid < 240){
        const int colp = tid>>4, ch = tid&15;
        const float* qb = P_.q + b*AA + ch*32;
        const float* w  = P_.aW2 + (ch*32)*15 + colp;
        float s=0.f;
        #pragma unroll 8
        for (int i=0;i<32;i++) s += qb[i]*w[i*15];
        sm[1024 + colp*16 + ch] = s;
      }
      __syncthreads();
      if (tid < 15){
        float s = P_.ab2[tid];
        #pragma unroll
        for (int i=0;i<16;i++) s += sm[1024+tid*16+i];
        sm[1264+tid] = s;
      }
      __syncthreads();
      if (tid == 0){
        float lo = 3.4e38f, hi = -3.4e38f, mmax = -3.4e38f;
        for (int k=0;k<KK;k++){
          float m  = mnsi[b*8+k] + softplusf(sm[1264+k]);
          sm[1280+k] = m;
          if (et == 0) mnso[b*8+k] = m;
          float sc = softplusf(sm[1264+5+k]) + 1e-4f;
          sm[1285+k] = sc;
          mmax = fmaxf(mmax, sm[1264+10+k]);
          lo = fminf(lo, m - 0.5f - 26.f*sc);   // e^-26 tail: skipped mass < 1e-11
          hi = fmaxf(hi, m + 0.5f + 26.f*sc);
        }
        float den = 0.f;
        for (int k=0;k<KK;k++){ float e = expf(sm[1264+10+k]-mmax); sm[1290+k]=e; den += e; }
        float rd = 1.f/den;
        for (int k=0;k<KK;k++) sm[1290+k] *= rd;
        int ilo = (int)fmaxf(0.f, floorf(lo));
        int ihi = (int)fminf((float)TT, ceilf(hi)+1.f);
        if (ihi < ilo) ihi = ilo;
        itlo = ilo; ithi = ihi;
      }
      __syncthreads();
      const int tlo = itlo, thi = ithi;
      for (int t = tlo + tid; t < thi; t += BT){
        float aw = 0.f;
        #pragma unroll
        for (int k=0;k<KK;k++){
          float mu = sm[1280+k], sc = sm[1285+k];
          float zh = ((float)t + 0.5f - mu)/sc;
          float zl = ((float)t - 0.5f - mu)/sc;
          aw += sm[1290+k]*(sigm(zh)-sigm(zl));
        }
        sm[t] = aw;
      }
      __syncthreads();
      const int e = et*128 + (tid & 127), oct = tid >> 7;   // oct 0..3
      const float* zb = P_.enc + (size_t)b*(TT*EE) + e;
      float acc = 0.f;
      for (int t = tlo + oct; t < thi; t += 4)
        acc += sm[t]*zb[(size_t)t*EE];
      sm[1300+tid] = acc;
      __syncthreads();
      if (tid < 128)
        P_.ctx[b*EE + et*128 + tid] = sm[1300+tid]+sm[1428+tid]+sm[1556+tid]+sm[1684+tid];
    }
    grid.sync();

    // ========== P5: LSTM1. block = (4 units x 4 gates) x (8 batches), 160 active ==========
    if (blk < 192){
      const int t3 = blk >> 3;                 // 0..23
      const int ug = (blk & 7) + 8*(t3 % 3);   // 0..23; active if <20
      const int bg = t3 / 3;                   // 0..7
      if (ug < 20){
        const int u0 = ug*4, bb0 = bg*8;
        for (int idx = tid; idx < 8*277; idx += BT){
          int r = idx/277, q4 = idx%277;
          float4 v;
          if (q4 < 128)      v = *(const float4*)&P_.ctx[(bb0+r)*EE + 4*q4];
          else if (q4 < 256) v = *(const float4*)&hout[(bb0+r)*AA + 4*(q4-128)];
          else               v = *(const float4*)&h1in[(bb0+r)*DD + 4*(q4-256)]; // q4=276 pads (unused)
          *(float4*)&sm[r*1108 + 4*q4] = v;
        }
        __syncthreads();
        const int c_ = tid&15, bl = (tid>>4)&7, jh = tid>>7;  // jh 0..3
        const int u_ = c_&3, g_ = c_>>2;
        const int col = g_*80 + u0 + u_;
        float a0=0,a1=0,a2=0,a3=0;
        {
          const int jstart = jh*276;
          const int nA = (jh < 3) ? 69 : 49;   // float4 count within lWx1 rows
          const float* xs = &sm[bl*1108 + jstart];
          const float* W  = P_.lWx1 + col + jstart*320;
          #pragma unroll 4
          for (int j4=0;j4<nA;++j4){
            float4 v = *(const float4*)(xs + 4*j4);
            a0 += v.x*W[0]; a1 += v.y*W[320]; a2 += v.z*W[640]; a3 += v.w*W[960];
            W += 1280;
          }
        }
        if (jh == 3){  // lWh1 rows 0..79
          const float* xs = &sm[bl*1108 + 1024];
          const float* W  = P_.lWh1 + col;
          #pragma unroll 5
          for (int j4=0;j4<20;++j4){
            float4 v = *(const float4*)(xs + 4*j4);
            a0 += v.x*W[0]; a1 += v.y*W[320]; a2 += v.z*W[640]; a3 += v.w*W[960];
            W += 1280;
          }
        }
        sm[8864+tid] = (a0+a1)+(a2+a3);
        __syncthreads();
        if (tid < 32){
          const int uu_ = tid&3, bb_ = tid>>2;
          float gate[4];
          #pragma unroll
          for (int g2=0;g2<4;g2++){
            int base = (uu_ + 4*g2) + 16*bb_;
            gate[g2] = sm[8864+base]+sm[8864+base+128]+sm[8864+base+256]+sm[8864+base+384]
                     + P_.lb1[g2*80 + u0+uu_];
          }
          float i_=sigm(gate[0]), f_=sigm(gate[1]), gg=tanhf(gate[2]), o_=sigm(gate[3]);
          const int bb = bb0+bb_, uu = u0+uu_;
          float cn = f_*P_.c1[bb*DD+uu] + i_*gg;
          P_.c1[bb*DD+uu] = cn;
          h1out[bb*DD+uu] = o_*tanhf(cn);
        }
      }
    }
    grid.sync();

    // ========== P6: LSTM2 + outputs + prenet. block = batch b, blk<64 ==========
    if (blk < BB){
      const int b = blk;
      if (tid < 20)                    *(float4*)&sm[4*tid]         = *(const float4*)&h1out[b*DD+4*tid];
      else if (tid >= 32 && tid < 52)  *(float4*)&sm[80+4*(tid-32)] = *(const float4*)&P_.h2[b*DD+4*(tid-32)];
      __syncthreads();
      if (tid < 320){
        float a0=0,a1=0,a2=0,a3=0;
        const float* W = P_.lWx2 + tid;
        #pragma unroll 4
        for (int j4=0;j4<20;++j4){
          float4 v = *(const float4*)&sm[4*j4];
          a0 += v.x*W[0]; a1 += v.y*W[320]; a2 += v.z*W[640]; a3 += v.w*W[960];
          W += 1280;
        }
        const float* W2 = P_.lWh2 + tid;
        #pragma unroll 4
        for (int j4=0;j4<20;++j4){
          float4 v = *(const float4*)&sm[80+4*j4];
          a0 += v.x*W2[0]; a1 += v.y*W2[320]; a2 += v.z*W2[640]; a3 += v.w*W2[960];
          W2 += 1280;
        }
        sm[160+tid] = (a0+a1)+(a2+a3) + P_.lb2[tid];
      }
      __syncthreads();
      if (tid < DD){
        float i_=sigm(sm[160+tid]), f_=sigm(sm[240+tid]), g2=tanhf(sm[320+tid]), o_=sigm(sm[400+tid]);
        float cn = f_*P_.c2[b*DD+tid] + i_*g2;
        P_.c2[b*DD+tid] = cn;
        float hn = o_*tanhf(cn);
        sm[480+tid] = hn;
        P_.h2[b*DD+tid] = hn;
        const size_t oidx = (size_t)(b*LL + l)*DD + tid;
        P_.oa[oidx]  = hn;
        P_.obf[oidx] = hn;
        sm[560+tid] = hn*P_.sW[tid];
      }
      __syncthreads();
      if (tid == 0){
        float s = P_.sb[0];
        for (int i=0;i<DD;i++) s += sm[560+i];
        P_.ol[b*LL + l] = s;
      }
      if (tid < DD){
        float s = P_.pb1[tid];
        #pragma unroll 8
        for (int i=0;i<DD;i++) s += sm[480+i]*P_.pW1[i*DD+tid];
        sm[640+tid] = fmaxf(s, 0.f);
      }
      __syncthreads();
      if (tid < DD){
        float s = P_.pb2[tid];
        #pragma unroll 8
        for (int i=0;i<DD;i++) s += sm[640+i]*P_.pW2[i*DD+tid];
        P_.p[b*DD+tid] = fmaxf(s, 0.f);
      }
    }
    grid.sync();
  }
}

extern "C" void kernel_launch(void* const* d_in, const int* in_sizes, int n_in,
                              void* d_out, int out_size, void* d_ws, size_t ws_size,
                              hipStream_t stream){
  (void)in_sizes; (void)n_in; (void)out_size;
  if (ws_size < (size_t)162816*sizeof(float)) return;

  Pr P_;
  P_.enc = (const float*)d_in[0];
  P_.pW1=(const float*)d_in[2];  P_.pb1=(const float*)d_in[3];
  P_.pW2=(const float*)d_in[4];  P_.pb2=(const float*)d_in[5];
  P_.gWx=(const float*)d_in[6];  P_.gWh=(const float*)d_in[7];
  P_.gbx=(const float*)d_in[8];  P_.gbh=(const float*)d_in[9];
  P_.aW1=(const float*)d_in[10]; P_.ab1=(const float*)d_in[11];
  P_.aW2=(const float*)d_in[12]; P_.ab2=(const float*)d_in[13];
  P_.lWx1=(const float*)d_in[14]; P_.lWh1=(const float*)d_in[15]; P_.lb1=(const float*)d_in[16];
  P_.lWx2=(const float*)d_in[17]; P_.lWh2=(const float*)d_in[18]; P_.lb2=(const float*)d_in[19];
  P_.sW=(const float*)d_in[20];  P_.sb=(const float*)d_in[21];

  float* ws = (float*)d_ws;
  P_.ha    = ws;           // 2 x 64x512
  P_.means = ws + 65536;   // 2 x 64x8
  P_.h1    = ws + 66560;   // 2 x 64x80
  P_.c1    = ws + 76800;   // 64x80
  P_.h2    = ws + 81920;   // 64x80
  P_.c2    = ws + 87040;   // 64x80
  P_.p     = ws + 92160;   // 64x80
  P_.q     = ws + 97280;   // 64x512
  P_.ctx   = ws + 130048;  // 64x512

  float* o = (float*)d_out;
  P_.oa  = o;
  P_.obf = o + (size_t)BB*LL*DD;
  P_.ol  = o + (size_t)2*BB*LL*DD;

  void* args[] = { (void*)&P_ };
  hipLaunchCooperativeKernel((void*)decoder_kernel, dim3(NB), dim3(BT), args, 0, stream);
}

// Round 4
// 95068.500 us; speedup vs baseline: 1.5618x; 1.2876x over previous
//
#include <hip/hip_runtime.h>
#include <hip/hip_cooperative_groups.h>

namespace cg = cooperative_groups;

#define NB 256      // 64 batches x 4-block cohorts
#define BT 512
#define BB 64
#define TT 1024
#define LL 400
#define EE 512
#define DD 80
#define AA 512
#define KK 5

// ws float offsets
#define WS_HB    4096     // [64][512]  hout exchange
#define WS_PPRM  36864    // [64][4][16] param partials
#define WS_PL1   40960    // [64][4][320] lstm1 partials
#define WS_TOTAL 122880

// LDS float offsets
#define S_XH    0      // 512 h_att
#define S_P     512    // 80  prenet out
#define S_H1    592    // 80
#define S_C1    672    // 80
#define S_H2    752    // 80
#define S_C2    832    // 80
#define S_MEANS 912    // 8
#define S_Q     920    // 128 own q slice
#define S_CTX   1048   // 128 own ctx slice
#define S_GATES 1176   // 320
#define S_PH    1496   // 80  prenet hidden / stop reduce
#define S_SRED  1576   // 24  (sc[5], mixw[5])
#define S_AW    1664   // 1024
#define S_SCR   2688   // 3072 reduce scratch (16B aligned: byte 10752)
#define S_TOT   5760

struct Pr {
  const float *enc;
  const float *pW1,*pb1,*pW2,*pb2;
  const float *gWx,*gWh,*gbx,*gbh;
  const float *aW1,*ab1,*aW2,*ab2;
  const float *lWx1,*lWh1,*lb1,*lWx2,*lWh2,*lb2;
  const float *sW,*sb;
  float *oa,*obf,*ol;
  unsigned *ctr;            // 64 counters, stride 64 u32
  float *hb,*pprm,*pl1;
};

__device__ __forceinline__ float sigm(float x){ return 1.f/(1.f+expf(-x)); }
__device__ __forceinline__ float softplusf(float x){ return fmaxf(x,0.f)+log1pf(expf(-fabsf(x))); }

__device__ __forceinline__ void gstore(float* p, float v){
  __hip_atomic_store(p, v, __ATOMIC_RELAXED, __HIP_MEMORY_SCOPE_AGENT);
}
__device__ __forceinline__ float gload(const float* p){
  return __hip_atomic_load(p, __ATOMIC_RELAXED, __HIP_MEMORY_SCOPE_AGENT);
}

// 4-block cohort barrier: monotonic counter, device-scope.
__device__ __forceinline__ void cbar(unsigned* ctr, unsigned& tgt){
  __threadfence();                 // drain my stores to coherence point
  __syncthreads();
  if (threadIdx.x == 0){
    __hip_atomic_fetch_add(ctr, 1u, __ATOMIC_RELEASE, __HIP_MEMORY_SCOPE_AGENT);
    while (__hip_atomic_load(ctr, __ATOMIC_ACQUIRE, __HIP_MEMORY_SCOPE_AGENT) < tgt)
      __builtin_amdgcn_s_sleep(8);
  }
  __syncthreads();
  __threadfence();                 // invalidate caches: see cohort-mates' data
  tgt += 4;
}

__global__ __launch_bounds__(BT) void decoder_kernel(Pr P){
  const int blk = blockIdx.x, tid = threadIdx.x;
  const int b = blk & 63, qd = blk >> 6;      // batch, quarter 0..3
  __shared__ float sm[S_TOT];
  __shared__ int itlo, ithi;
  unsigned* ctr = P.ctr + (size_t)b*64;

  // zero barrier counters once, grid-wide sync once
  for (int i = blk*BT+tid; i < 4096; i += NB*BT) P.ctr[i] = 0u;
  cg::this_grid().sync();

  for (int i = tid; i < S_TOT; i += BT) sm[i] = 0.f;
  __syncthreads();

  unsigned tgt = 4;

  for (int l=0; l<LL; ++l){
    // ======= prenet (redundant): p = relu(relu(h2@pW1+b1)@pW2+b2) =======
    {
      if (tid < 160){
        const int f4 = tid % 20, jh = tid / 20;     // 8 jh x 10 rows
        float4 a = {0,0,0,0};
        const float* W = P.pW1 + (jh*10)*80 + 4*f4;
        #pragma unroll
        for (int r=0;r<10;++r){
          float x = sm[S_H2 + jh*10 + r];
          float4 w = *(const float4*)W; W += 80;
          a.x += x*w.x; a.y += x*w.y; a.z += x*w.z; a.w += x*w.w;
        }
        ((float4*)&sm[S_SCR])[jh*20+f4] = a;
      }
      __syncthreads();
      if (tid < 80){
        float s = P.pb1[tid];
        #pragma unroll
        for (int jh=0;jh<8;++jh) s += sm[S_SCR + jh*80 + tid];
        sm[S_PH + tid] = fmaxf(s, 0.f);
      }
      __syncthreads();
      if (tid < 160){
        const int f4 = tid % 20, jh = tid / 20;
        float4 a = {0,0,0,0};
        const float* W = P.pW2 + (jh*10)*80 + 4*f4;
        #pragma unroll
        for (int r=0;r<10;++r){
          float x = sm[S_PH + jh*10 + r];
          float4 w = *(const float4*)W; W += 80;
          a.x += x*w.x; a.y += x*w.y; a.z += x*w.z; a.w += x*w.w;
        }
        ((float4*)&sm[S_SCR])[jh*20+f4] = a;
      }
      __syncthreads();
      if (tid < 80){
        float s = P.pb2[tid];
        #pragma unroll
        for (int jh=0;jh<8;++jh) s += sm[S_SCR + jh*80 + tid];
        sm[S_P + tid] = fmaxf(s, 0.f);
      }
      __syncthreads();
    }

    // ======= GRU unit-split: units [128qd..128qd+128) =======
    {
      const int U0 = 128*qd;
      if (tid < 384){
        const int f4 = tid % 96, jh = tid / 96;       // 4 jh
        const int g = f4 >> 5, i4 = f4 & 31;          // gate strip, f4 in strip
        const int cb = g*512 + U0 + 4*i4;
        float4 aX={0,0,0,0}, aH={0,0,0,0};
        { const float* W = P.gWx + (jh*20)*1536 + cb;
          #pragma unroll 4
          for (int r=0;r<20;++r){
            float x = sm[S_P + jh*20 + r];
            float4 w = *(const float4*)W; W += 1536;
            aX.x += x*w.x; aX.y += x*w.y; aX.z += x*w.z; aX.w += x*w.w;
          } }
        { const float* W = P.gWh + (jh*128)*1536 + cb;
          #pragma unroll 4
          for (int r=0;r<128;++r){
            float x = sm[S_XH + jh*128 + r];
            float4 w = *(const float4*)W; W += 1536;
            aH.x += x*w.x; aH.y += x*w.y; aH.z += x*w.z; aH.w += x*w.w;
          } }
        ((float4*)&sm[S_SCR])[jh*96 + f4] = aX;
        ((float4*)&sm[S_SCR])[384 + jh*96 + f4] = aH;
      }
      __syncthreads();
      if (tid < 128){
        const int u = tid, c0 = U0 + u;
        float xg[3], hg[3];
        #pragma unroll
        for (int g=0; g<3; ++g){
          float sx=0.f, sh=0.f;
          #pragma unroll
          for (int jh=0;jh<4;++jh){
            sx += sm[S_SCR + jh*384 + g*128 + u];
            sh += sm[S_SCR + 1536 + jh*384 + g*128 + u];
          }
          xg[g]=sx; hg[g]=sh;
        }
        float r = sigm(xg[0]+hg[0] + P.gbx[c0] + P.gbh[c0]);
        float z = sigm(xg[1]+hg[1] + P.gbx[512+c0] + P.gbh[512+c0]);
        float n = tanhf(xg[2] + P.gbx[1024+c0] + r*(hg[2] + P.gbh[1024+c0]));
        float ho = (1.f-z)*n + z*sm[S_XH + c0];
        gstore(&P.hb[b*512 + c0], ho);
      }
      cbar(ctr, tgt);                        // ---- barrier A: hout ready
      sm[S_XH + tid] = gload(&P.hb[b*512 + tid]);
      __syncthreads();
    }

    // ======= q slice [128qd..) + param partials (j over own slice) =======
    {
      if (tid < 256){
        const int i4 = tid & 31, jh = tid >> 5;       // 8 jh x 64 rows
        const int cb = 128*qd + 4*i4;
        float4 a={0,0,0,0};
        const float* W = P.aW1 + (jh*64)*512 + cb;
        #pragma unroll 4
        for (int r=0;r<64;++r){
          float x = sm[S_XH + jh*64 + r];
          float4 w = *(const float4*)W; W += 512;
          a.x += x*w.x; a.y += x*w.y; a.z += x*w.z; a.w += x*w.w;
        }
        ((float4*)&sm[S_SCR])[jh*32 + i4] = a;
      }
      __syncthreads();
      if (tid < 128){
        float s = 0.f;
        #pragma unroll
        for (int jh=0;jh<8;++jh) s += sm[S_SCR + jh*128 + tid];
        sm[S_Q + tid] = tanhf(s + P.ab1[128*qd + tid]);
      }
      __syncthreads();
      if (tid < 240){
        const int col = tid >> 4, ch = tid & 15;      // 15 cols x 16 chunks(8)
        float s = 0.f;
        const float* W = P.aW2 + (128*qd + ch*8)*15 + col;
        #pragma unroll
        for (int r=0;r<8;++r){ s += sm[S_Q + ch*8 + r] * W[0]; W += 15; }
        sm[S_SCR + col*16 + ch] = s;
      }
      __syncthreads();
      if (tid < 15){
        float s = 0.f;
        #pragma unroll
        for (int ch=0;ch<16;++ch) s += sm[S_SCR + tid*16 + ch];
        gstore(&P.pprm[b*64 + qd*16 + tid], s);
      }
      cbar(ctr, tgt);                        // ---- barrier B: params ready
    }

    // ======= mixture (redundant) + attn weights + ctx slice =======
    {
      if (tid == 0){
        float pv[15];
        #pragma unroll
        for (int c=0;c<15;++c){
          float s = P.ab2[c];
          #pragma unroll
          for (int qq=0;qq<4;++qq) s += gload(&P.pprm[b*64 + qq*16 + c]);
          pv[c] = s;
        }
        float lo=3.4e38f, hi=-3.4e38f, mmax=-3.4e38f;
        #pragma unroll
        for (int k=0;k<KK;++k){
          float m = sm[S_MEANS+k] + softplusf(pv[k]);
          sm[S_MEANS+k] = m;
          float s = softplusf(pv[5+k]) + 1e-4f;
          sm[S_SRED+k] = s;
          mmax = fmaxf(mmax, pv[10+k]);
          lo = fminf(lo, m - 0.5f - 26.f*s);   // e^-26 tail: mass < 1e-11
          hi = fmaxf(hi, m + 0.5f + 26.f*s);
        }
        float den=0.f;
        #pragma unroll
        for (int k=0;k<KK;++k){ float e = expf(pv[10+k]-mmax); sm[S_SRED+5+k]=e; den+=e; }
        float rd = 1.f/den;
        #pragma unroll
        for (int k=0;k<KK;++k) sm[S_SRED+5+k] *= rd;
        int ilo = (int)fmaxf(0.f, floorf(lo));
        int ihi = (int)fminf((float)TT, ceilf(hi)+1.f);
        if (ihi < ilo) ihi = ilo;
        itlo = ilo; ithi = ihi;
      }
      __syncthreads();
      const int tlo = itlo, thi = ithi;
      for (int t = tlo + tid; t < thi; t += BT){
        float aw = 0.f;
        #pragma unroll
        for (int k=0;k<KK;++k){
          float mu = sm[S_MEANS+k], s = sm[S_SRED+k];
          float zh = ((float)t + 0.5f - mu)/s;
          float zl = ((float)t - 0.5f - mu)/s;
          aw += sm[S_SRED+5+k]*(sigm(zh)-sigm(zl));
        }
        sm[S_AW + t] = aw;
      }
      __syncthreads();
      {
        const int e = tid & 127, ts = tid >> 7;
        const float* zb = P.enc + (size_t)b*(TT*EE) + 128*qd + e;
        float acc = 0.f;
        for (int t = tlo + ts; t < thi; t += 4)
          acc += sm[S_AW + t] * zb[(size_t)t*EE];
        sm[S_SCR + ts*128 + e] = acc;
      }
      __syncthreads();
      if (tid < 128)
        sm[S_CTX + tid] = sm[S_SCR+tid]+sm[S_SCR+128+tid]+sm[S_SCR+256+tid]+sm[S_SCR+384+tid];
      __syncthreads();
    }

    // ======= LSTM1 j-split: rows = own ctx(128) + own hout(128) + own h1(20) =======
    {
      if (tid < 320){
        const int f4 = tid % 80, jh = tid / 80;       // 4 jh x 69 rows
        float4 a={0,0,0,0};
        for (int rr=0; rr<69; ++rr){
          const int r = jh*69 + rr;
          float xv; const float* W;
          if (r < 128){      xv = sm[S_CTX + r];                 W = P.lWx1 + (128*qd + r)*320; }
          else if (r < 256){ xv = sm[S_XH + 128*qd + (r-128)];   W = P.lWx1 + (512 + 128*qd + (r-128))*320; }
          else {             xv = sm[S_H1 + 20*qd + (r-256)];    W = P.lWh1 + (20*qd + (r-256))*320; }
          float4 w = *(const float4*)(W + 4*f4);
          a.x += xv*w.x; a.y += xv*w.y; a.z += xv*w.z; a.w += xv*w.w;
        }
        ((float4*)&sm[S_SCR])[jh*80 + f4] = a;
      }
      __syncthreads();
      if (tid < 320){
        float s = 0.f;
        #pragma unroll
        for (int jh=0;jh<4;++jh) s += sm[S_SCR + jh*320 + tid];
        gstore(&P.pl1[b*1280 + qd*320 + tid], s);
      }
      cbar(ctr, tgt);                        // ---- barrier C: lstm1 partials
      if (tid < 320){
        float s = P.lb1[tid];
        #pragma unroll
        for (int qq=0;qq<4;++qq) s += gload(&P.pl1[b*1280 + qq*320 + tid]);
        sm[S_GATES + tid] = s;
      }
      __syncthreads();
      if (tid < 80){
        float i_ = sigm(sm[S_GATES+tid]);
        float f_ = sigm(sm[S_GATES+80+tid]);
        float g_ = tanhf(sm[S_GATES+160+tid]);
        float o_ = sigm(sm[S_GATES+240+tid]);
        float cn = f_*sm[S_C1+tid] + i_*g_;
        sm[S_C1+tid] = cn;
        sm[S_H1+tid] = o_*tanhf(cn);
      }
      __syncthreads();
    }

    // ======= LSTM2 (redundant) + outputs =======
    {
      if (tid < 320){
        const int f4 = tid % 80, jh = tid / 80;       // 4 jh x 40 rows
        float4 a={0,0,0,0};
        #pragma unroll 4
        for (int rr=0; rr<40; ++rr){
          const int r = jh*40 + rr;
          float xv; const float* W;
          if (r < 80){ xv = sm[S_H1 + r];      W = P.lWx2 + r*320; }
          else {       xv = sm[S_H2 + r - 80]; W = P.lWh2 + (r-80)*320; }
          float4 w = *(const float4*)(W + 4*f4);
          a.x += xv*w.x; a.y += xv*w.y; a.z += xv*w.z; a.w += xv*w.w;
        }
        ((float4*)&sm[S_SCR])[jh*80 + f4] = a;
      }
      __syncthreads();
      if (tid < 320){
        float s = P.lb2[tid];
        #pragma unroll
        for (int jh=0;jh<4;++jh) s += sm[S_SCR + jh*320 + tid];
        sm[S_GATES + tid] = s;
      }
      __syncthreads();
      if (tid < 80){
        float i_ = sigm(sm[S_GATES+tid]);
        float f_ = sigm(sm[S_GATES+80+tid]);
        float g_ = tanhf(sm[S_GATES+160+tid]);
        float o_ = sigm(sm[S_GATES+240+tid]);
        float cn = f_*sm[S_C2+tid] + i_*g_;
        sm[S_C2+tid] = cn;
        float hn = o_*tanhf(cn);
        sm[S_H2+tid] = hn;
        sm[S_PH+tid] = hn * P.sW[tid];
        if (qd == 0){
          const size_t oidx = ((size_t)b*LL + l)*DD + tid;
          P.oa[oidx]  = hn;
          P.obf[oidx] = hn;
        }
      }
      __syncthreads();
      if (tid == 0 && qd == 0){
        float s = P.sb[0];
        for (int i=0;i<DD;++i) s += sm[S_PH+i];
        P.ol[b*LL + l] = s;
      }
      __syncthreads();
    }
  }
}

extern "C" void kernel_launch(void* const* d_in, const int* in_sizes, int n_in,
                              void* d_out, int out_size, void* d_ws, size_t ws_size,
                              hipStream_t stream){
  (void)in_sizes; (void)n_in; (void)out_size;
  if (ws_size < (size_t)WS_TOTAL*sizeof(float)) return;

  Pr P;
  P.enc = (const float*)d_in[0];
  P.pW1=(const float*)d_in[2];  P.pb1=(const float*)d_in[3];
  P.pW2=(const float*)d_in[4];  P.pb2=(const float*)d_in[5];
  P.gWx=(const float*)d_in[6];  P.gWh=(const float*)d_in[7];
  P.gbx=(const float*)d_in[8];  P.gbh=(const float*)d_in[9];
  P.aW1=(const float*)d_in[10]; P.ab1=(const float*)d_in[11];
  P.aW2=(const float*)d_in[12]; P.ab2=(const float*)d_in[13];
  P.lWx1=(const float*)d_in[14]; P.lWh1=(const float*)d_in[15]; P.lb1=(const float*)d_in[16];
  P.lWx2=(const float*)d_in[17]; P.lWh2=(const float*)d_in[18]; P.lb2=(const float*)d_in[19];
  P.sW=(const float*)d_in[20];  P.sb=(const float*)d_in[21];

  float* ws = (float*)d_ws;
  P.ctr  = (unsigned*)ws;          // [0..4096) u32 counters (stride 64)
  P.hb   = ws + WS_HB;
  P.pprm = ws + WS_PPRM;
  P.pl1  = ws + WS_PL1;

  float* o = (float*)d_out;
  P.oa  = o;
  P.obf = o + (size_t)BB*LL*DD;
  P.ol  = o + (size_t)2*BB*LL*DD;

  void* args[] = { (void*)&P };
  hipLaunchCooperativeKernel((void*)decoder_kernel, dim3(NB), dim3(BT), args, 0, stream);
}

// Round 5
// 41724.686 us; speedup vs baseline: 3.5585x; 2.2785x over previous
//
#include <hip/hip_runtime.h>

#define NB 64       // 16 cohorts x 4 qd-blocks
#define BT 512
#define BB 64
#define TT 1024
#define LL 400
#define EE 512
#define DD 80
#define AA 512
#define KK 5

// ws float offsets
#define WF_HB    1024     // [64][512] hout exchange
#define WF_PL1   33792    // [64][4][320] lstm1 partials
#define WF_TOTAL 115712   // floats

struct Pr {
  const float *enc;
  const float *pW1,*pb1,*pW2,*pb2;
  const float *gWx,*gWh,*gbx,*gbh;
  const float *aW1,*ab1,*aW2,*ab2;
  const float *lWx1,*lWh1,*lb1,*lWx2,*lWh2,*lb2;
  const float *sW,*sb;
  float *oa,*obf,*ol;
  unsigned *ctr;            // 16 counters, stride 64 u32
  float *hb,*pl1;
};

__device__ __forceinline__ float sigm(float x){ return 1.f/(1.f+expf(-x)); }
__device__ __forceinline__ float softplusf(float x){ return fmaxf(x,0.f)+log1pf(expf(-fabsf(x))); }
__device__ __forceinline__ void gstore(float* p, float v){
  __hip_atomic_store(p, v, __ATOMIC_RELAXED, __HIP_MEMORY_SCOPE_AGENT);
}
__device__ __forceinline__ float gload(const float* p){
  return __hip_atomic_load(p, __ATOMIC_RELAXED, __HIP_MEMORY_SCOPE_AGENT);
}
__device__ __forceinline__ void acc4(float4& a, float w, const float4 x){
  a.x = fmaf(w,x.x,a.x); a.y = fmaf(w,x.y,a.y);
  a.z = fmaf(w,x.z,a.z); a.w = fmaf(w,x.w,a.w);
}

// 4-block cohort barrier — NO cache-maintenance (no threadfence/acquire).
// Data exchange uses memory-side relaxed atomics; visibility ordering comes
// from vmcnt drain + the counter handshake.
__device__ __forceinline__ void cbar(unsigned* ctr, unsigned& tgt){
  __syncthreads();
  if (threadIdx.x == 0){
    asm volatile("s_waitcnt vmcnt(0)" ::: "memory");
    __hip_atomic_fetch_add(ctr, 1u, __ATOMIC_RELAXED, __HIP_MEMORY_SCOPE_AGENT);
    while (__hip_atomic_load(ctr, __ATOMIC_RELAXED, __HIP_MEMORY_SCOPE_AGENT) < tgt)
      __builtin_amdgcn_s_sleep(2);
  }
  __syncthreads();
  tgt += 4;
}

__global__ __launch_bounds__(BT) void decoder_kernel(Pr P){
  const int blk = blockIdx.x, tid = threadIdx.x;
  const int qd = blk & 3, coh = blk >> 2;       // XCD=blk%8 -> qd fixed per XCD
  const int b0 = coh * 4;                       // batches b0..b0+3
  unsigned* ctr = P.ctr + coh*64;

  __shared__ __align__(16) float hj4[512][4];   // h_att packed [j][g]
  __shared__ __align__(16) float qj4[512][4];
  __shared__ __align__(16) float pj4[80][4];
  __shared__ __align__(16) float h1j4[80][4];
  __shared__ __align__(16) float h2j4[80][4];
  __shared__ float c1s[4][80], c2s[4][80];
  __shared__ float ctxs[4][128];
  __shared__ float aw[4][1024];
  __shared__ __align__(16) float scr[8192];
  __shared__ __align__(16) float X1[280][4];
  __shared__ float pv[4][16], mstate[4][8], mscale[4][8], mw[4][8];
  __shared__ int wlo[4], whi[4];

  // zero recurrent LDS state
  for (int i=tid;i<2048;i+=BT) hj4[i>>2][i&3]=0.f;
  for (int i=tid;i<320;i+=BT){ h1j4[i>>2][i&3]=0.f; h2j4[i>>2][i&3]=0.f; }
  for (int i=tid;i<320;i+=BT){ c1s[i>>6][i&63]=0.f; c2s[i>>6][i&63]=0.f; }  // 4*80=320: map below
  if (tid<320){ c1s[tid&3][tid>>2]=0.f; c2s[tid&3][tid>>2]=0.f; }
  if (tid<32) mstate[tid>>3][tid&7]=0.f;
  __syncthreads();

  unsigned tgt = 4;

  for (int l=0; l<LL; ++l){
    // ===== P0: prenet (redundant; input h2) =====
    if (tid<320){
      const int col=tid>>2, g=tid&3;
      float s=P.pb1[col];
      #pragma unroll 4
      for (int j=0;j<80;++j) s += h2j4[j][g]*P.pW1[j*80+col];
      scr[col*4+g]=fmaxf(s,0.f);
    }
    __syncthreads();
    if (tid<320){
      const int col=tid>>2, g=tid&3;
      float s=P.pb2[col];
      #pragma unroll 4
      for (int j=0;j<80;++j) s += scr[j*4+g]*P.pW2[j*80+col];
      pj4[col][g]=fmaxf(s,0.f);
    }
    __syncthreads();

    // ===== P1: GRU slice (units qd*128..+128), batch-amortized weights =====
    {
      const int u = tid & 127, jh = tid >> 7;   // 4 jh x 148 j
      const int cb = qd*128 + u;
      float4 a_r={0,0,0,0}, a_z={0,0,0,0}, a_xn={0,0,0,0}, a_hn={0,0,0,0};
      const int j0 = jh*148;
      #pragma unroll 4
      for (int jj=0; jj<148; ++jj){
        const int j = j0 + jj;
        if (j < 80){
          float4 x = *(const float4*)pj4[j];
          const float* W = P.gWx + (size_t)j*1536 + cb;
          acc4(a_r, W[0], x); acc4(a_z, W[512], x); acc4(a_xn, W[1024], x);
        } else {
          float4 x = *(const float4*)hj4[j-80];
          const float* W = P.gWh + (size_t)(j-80)*1536 + cb;
          acc4(a_r, W[0], x); acc4(a_z, W[512], x); acc4(a_hn, W[1024], x);
        }
      }
      float4* s4 = (float4*)scr;
      const int base = (jh*128+u)*4;
      s4[base+0]=a_r; s4[base+1]=a_z; s4[base+2]=a_xn; s4[base+3]=a_hn;
    }
    __syncthreads();
    {
      const int g = tid>>7, u2 = tid&127;
      float rx=0,zx=0,xn=0,hn=0;
      #pragma unroll
      for (int jh=0;jh<4;++jh){
        const int base = ((jh*128+u2)*4)*4;
        rx += scr[base + 0 + g];
        zx += scr[base + 4 + g];
        xn += scr[base + 8 + g];
        hn += scr[base + 12 + g];
      }
      const int uu = qd*128+u2;
      float r = sigm(rx + P.gbx[uu] + P.gbh[uu]);
      float z = sigm(zx + P.gbx[512+uu] + P.gbh[512+uu]);
      float n = tanhf(xn + P.gbx[1024+uu] + r*(hn + P.gbh[1024+uu]));
      float ho = (1.f-z)*n + z*hj4[uu][g];
      gstore(&P.hb[(size_t)(b0+g)*512 + uu], ho);
    }
    cbar(ctr, tgt);                             // ---- barrier A: hout
    {
      const int g = tid>>7, jb = tid&127;
      #pragma unroll
      for (int k=0;k<4;++k){
        const int j = jb + 128*k;
        hj4[j][g] = gload(&P.hb[(size_t)(b0+g)*512 + j]);
      }
    }
    __syncthreads();

    // ===== P2: q = tanh(h@aW1+b1) (redundant, full 512 cols) =====
    {
      const int c = tid;
      float4 a={0,0,0,0};
      const float* W = P.aW1 + c;
      #pragma unroll 8
      for (int j=0;j<512;++j){
        float w = W[(size_t)j*512];
        float4 x = *(const float4*)hj4[j];
        acc4(a, w, x);
      }
      float bb = P.ab1[c];
      qj4[c][0]=tanhf(a.x+bb); qj4[c][1]=tanhf(a.y+bb);
      qj4[c][2]=tanhf(a.z+bb); qj4[c][3]=tanhf(a.w+bb);
    }
    __syncthreads();
    // params partials: 15 cols x 4 g x 8 jh
    if (tid<480){
      const int col = tid%15, rem = tid/15;
      const int g = rem&3, jh = rem>>2;
      const int j0 = jh*64;
      float s=0.f;
      #pragma unroll 4
      for (int jj=0;jj<64;++jj) s += qj4[j0+jj][g]*P.aW2[(size_t)(j0+jj)*15+col];
      scr[(jh*4+g)*15+col] = s;
    }
    __syncthreads();
    if (tid<60){
      const int g = tid/15, col = tid%15;
      float s = P.ab2[col];
      #pragma unroll
      for (int jh=0;jh<8;++jh) s += scr[(jh*4+g)*15+col];
      pv[g][col]=s;
    }
    __syncthreads();
    if (tid<4){
      const int g = tid;
      float lo=3.4e38f, hi=-3.4e38f, mmax=-3.4e38f;
      #pragma unroll
      for (int k=0;k<KK;++k){
        float m = mstate[g][k] + softplusf(pv[g][k]);
        mstate[g][k]=m;
        float sc = softplusf(pv[g][5+k]) + 1e-4f;
        mscale[g][k]=sc;
        mmax = fmaxf(mmax, pv[g][10+k]);
        lo = fminf(lo, m-0.5f-26.f*sc);          // e^-26 tail: mass < 1e-11
        hi = fmaxf(hi, m+0.5f+26.f*sc);
      }
      float den=0.f;
      #pragma unroll
      for (int k=0;k<KK;++k){ float e=expf(pv[g][10+k]-mmax); mw[g][k]=e; den+=e; }
      float rd=1.f/den;
      #pragma unroll
      for (int k=0;k<KK;++k) mw[g][k]*=rd;
      int ilo=(int)fmaxf(0.f,floorf(lo));
      int ihi=(int)fminf((float)TT,ceilf(hi)+1.f);
      if (ihi<ilo) ihi=ilo;
      wlo[g]=ilo; whi[g]=ihi;
    }
    __syncthreads();

    // ===== P3: attention weights + ctx slice (e-range qd*128..+128) =====
    {
      const int g = tid&3, tl = tid>>2;
      for (int t = wlo[g]+tl; t < whi[g]; t += 128){
        float s=0.f; const float tf=(float)t;
        #pragma unroll
        for (int k=0;k<KK;++k){
          float mu=mstate[g][k], sc=mscale[g][k];
          s += mw[g][k]*(sigm((tf+0.5f-mu)/sc)-sigm((tf-0.5f-mu)/sc));
        }
        aw[g][t]=s;
      }
    }
    __syncthreads();
    {
      const int eq = tid&31, g = (tid>>5)&3, ts = tid>>7;
      const float* bz = P.enc + (size_t)(b0+g)*TT*EE + qd*128 + eq*4;
      float4 acc={0,0,0,0};
      int t = wlo[g]+ts; const int te = whi[g];
      for (; t+4 < te; t += 8){
        float a0=aw[g][t], a1=aw[g][t+4];
        float4 v0=*(const float4*)(bz+(size_t)t*EE);
        float4 v1=*(const float4*)(bz+(size_t)(t+4)*EE);
        acc.x = fmaf(a0,v0.x,fmaf(a1,v1.x,acc.x));
        acc.y = fmaf(a0,v0.y,fmaf(a1,v1.y,acc.y));
        acc.z = fmaf(a0,v0.z,fmaf(a1,v1.z,acc.z));
        acc.w = fmaf(a0,v0.w,fmaf(a1,v1.w,acc.w));
      }
      for (; t < te; t += 4){
        float a0=aw[g][t];
        float4 v=*(const float4*)(bz+(size_t)t*EE);
        acc4(acc, a0, v);
      }
      ((float4*)scr)[ts*128 + g*32 + eq] = acc;
    }
    __syncthreads();
    {
      const int g = tid>>7, e = tid&127;
      const int sl = g*32 + (e>>2), cp = e&3;
      ctxs[g][e] = scr[(0*128+sl)*4+cp] + scr[(1*128+sl)*4+cp]
                 + scr[(2*128+sl)*4+cp] + scr[(3*128+sl)*4+cp];
    }
    __syncthreads();

    // ===== P4: LSTM1 partials (j-slice by qd) =====
    for (int idx=tid; idx<1104; idx+=BT){
      const int r = idx>>2, g = idx&3;
      float v;
      if (r<128)      v = ctxs[g][r];
      else if (r<256) v = hj4[qd*128 + (r-128)][g];
      else            v = h1j4[qd*20 + (r-256)][g];
      X1[r][g]=v;
    }
    __syncthreads();
    if (tid<320){
      const int col=tid;
      float4 a={0,0,0,0};
      { const float* W = P.lWx1 + (size_t)(qd*128)*320 + col;
        #pragma unroll 4
        for (int r=0;r<128;++r){ acc4(a, W[(size_t)r*320], *(const float4*)X1[r]); } }
      { const float* W = P.lWx1 + (size_t)(512+qd*128)*320 + col;
        #pragma unroll 4
        for (int r=0;r<128;++r){ acc4(a, W[(size_t)r*320], *(const float4*)X1[128+r]); } }
      { const float* W = P.lWh1 + (size_t)(qd*20)*320 + col;
        #pragma unroll 4
        for (int r=0;r<20;++r){ acc4(a, W[(size_t)r*320], *(const float4*)X1[256+r]); } }
      gstore(&P.pl1[(size_t)(b0+0)*1280 + qd*320 + col], a.x);
      gstore(&P.pl1[(size_t)(b0+1)*1280 + qd*320 + col], a.y);
      gstore(&P.pl1[(size_t)(b0+2)*1280 + qd*320 + col], a.z);
      gstore(&P.pl1[(size_t)(b0+3)*1280 + qd*320 + col], a.w);
    }
    cbar(ctr, tgt);                             // ---- barrier C: partials
    if (tid<320){
      const int col=tid;
      const float bb=P.lb1[col];
      float4 s={bb,bb,bb,bb};
      #pragma unroll
      for (int qq=0;qq<4;++qq){
        s.x += gload(&P.pl1[(size_t)(b0+0)*1280 + qq*320 + col]);
        s.y += gload(&P.pl1[(size_t)(b0+1)*1280 + qq*320 + col]);
        s.z += gload(&P.pl1[(size_t)(b0+2)*1280 + qq*320 + col]);
        s.w += gload(&P.pl1[(size_t)(b0+3)*1280 + qq*320 + col]);
      }
      ((float4*)scr)[col]=s;
    }
    __syncthreads();
    if (tid<320){
      const int u=tid>>2, g=tid&3;
      float i_=sigm(scr[(0  +u)*4+g]);
      float f_=sigm(scr[(80 +u)*4+g]);
      float gg=tanhf(scr[(160+u)*4+g]);
      float o_=sigm(scr[(240+u)*4+g]);
      float cn=f_*c1s[g][u]+i_*gg;
      c1s[g][u]=cn;
      h1j4[u][g]=o_*tanhf(cn);
    }
    __syncthreads();

    // ===== P5: LSTM2 (redundant) + outputs =====
    if (tid<320){
      const int col=tid;
      float4 a={0,0,0,0};
      { const float* W=P.lWx2+col;
        #pragma unroll 4
        for (int r=0;r<80;++r){ acc4(a, W[(size_t)r*320], *(const float4*)h1j4[r]); } }
      { const float* W=P.lWh2+col;
        #pragma unroll 4
        for (int r=0;r<80;++r){ acc4(a, W[(size_t)r*320], *(const float4*)h2j4[r]); } }
      const float bb=P.lb2[col];
      a.x+=bb; a.y+=bb; a.z+=bb; a.w+=bb;
      ((float4*)scr)[col]=a;
    }
    __syncthreads();
    if (tid<320){
      const int u=tid>>2, g=tid&3;
      float i_=sigm(scr[(0  +u)*4+g]);
      float f_=sigm(scr[(80 +u)*4+g]);
      float gg=tanhf(scr[(160+u)*4+g]);
      float o_=sigm(scr[(240+u)*4+g]);
      float cn=f_*c2s[g][u]+i_*gg;
      c2s[g][u]=cn;
      float hn=o_*tanhf(cn);
      h2j4[u][g]=hn;
      scr[1280 + u*4+g]=hn*P.sW[u];
      if (qd==0){
        const size_t o=((size_t)(b0+g)*LL+l)*DD+u;
        P.oa[o]=hn; P.obf[o]=hn;
      }
    }
    __syncthreads();
    if (tid<4 && qd==0){
      float s=P.sb[0];
      for (int u=0;u<80;++u) s+=scr[1280+u*4+tid];
      P.ol[(size_t)(b0+tid)*LL+l]=s;
    }
    __syncthreads();
  }
}

extern "C" void kernel_launch(void* const* d_in, const int* in_sizes, int n_in,
                              void* d_out, int out_size, void* d_ws, size_t ws_size,
                              hipStream_t stream){
  (void)in_sizes; (void)n_in; (void)out_size;
  if (ws_size < (size_t)WF_TOTAL*sizeof(float)) return;

  hipMemsetAsync(d_ws, 0, 4096, stream);   // zero cohort barrier counters

  Pr P;
  P.enc = (const float*)d_in[0];
  P.pW1=(const float*)d_in[2];  P.pb1=(const float*)d_in[3];
  P.pW2=(const float*)d_in[4];  P.pb2=(const float*)d_in[5];
  P.gWx=(const float*)d_in[6];  P.gWh=(const float*)d_in[7];
  P.gbx=(const float*)d_in[8];  P.gbh=(const float*)d_in[9];
  P.aW1=(const float*)d_in[10]; P.ab1=(const float*)d_in[11];
  P.aW2=(const float*)d_in[12]; P.ab2=(const float*)d_in[13];
  P.lWx1=(const float*)d_in[14]; P.lWh1=(const float*)d_in[15]; P.lb1=(const float*)d_in[16];
  P.lWx2=(const float*)d_in[17]; P.lWh2=(const float*)d_in[18]; P.lb2=(const float*)d_in[19];
  P.sW=(const float*)d_in[20];  P.sb=(const float*)d_in[21];

  float* ws = (float*)d_ws;
  P.ctr = (unsigned*)ws;           // [0..1024) u32
  P.hb  = ws + WF_HB;              // [64][512]
  P.pl1 = ws + WF_PL1;             // [64][4][320]

  float* o = (float*)d_out;
  P.oa  = o;
  P.obf = o + (size_t)BB*LL*DD;
  P.ol  = o + (size_t)2*BB*LL*DD;

  void* args[] = { (void*)&P };
  hipLaunchCooperativeKernel((void*)decoder_kernel, dim3(NB), dim3(BT), args, 0, stream);
}

// Round 6
// 17627.400 us; speedup vs baseline: 8.4232x; 2.3670x over previous
//
#include <hip/hip_runtime.h>

#define NB 256      // 16 cohorts x 16 slice-blocks
#define BT 512
#define BB 64
#define TT 1024
#define LL 400
#define EE 512
#define DD 80
#define AA 512
#define KK 5

// ws float offsets
#define WF_HB    1024     // [64][512]  hout exchange
#define WF_PP    33792    // [64][16][16] param partials
#define WF_PL1   50176    // [64][16][320] lstm1 partials
#define WF_TOTAL 377856   // floats

struct Pr {
  const float *enc;
  const float *pW1,*pb1,*pW2,*pb2;
  const float *gWx,*gWh,*gbx,*gbh;
  const float *aW1,*ab1,*aW2,*ab2;
  const float *lWx1,*lWh1,*lb1,*lWx2,*lWh2,*lb2;
  const float *sW,*sb;
  float *oa,*obf,*ol;
  unsigned *ctr;            // 16 counters, stride 64 u32
  float *hb,*pp,*pl1;
};

__device__ __forceinline__ float sigm(float x){ return 1.f/(1.f+expf(-x)); }
__device__ __forceinline__ float softplusf(float x){ return fmaxf(x,0.f)+log1pf(expf(-fabsf(x))); }
__device__ __forceinline__ void gstore(float* p, float v){
  __hip_atomic_store(p, v, __ATOMIC_RELAXED, __HIP_MEMORY_SCOPE_AGENT);
}
__device__ __forceinline__ float gload(const float* p){
  return __hip_atomic_load(p, __ATOMIC_RELAXED, __HIP_MEMORY_SCOPE_AGENT);
}
__device__ __forceinline__ void acc4(float4& a, float w, const float4 x){
  a.x = fmaf(w,x.x,a.x); a.y = fmaf(w,x.y,a.y);
  a.z = fmaf(w,x.z,a.z); a.w = fmaf(w,x.w,a.w);
}

// 16-block cohort barrier — fence-free (relaxed agent-scope atomics; each
// wave's stores are drained by the vmcnt(0) the compiler emits for
// __syncthreads; no L2 writeback/invalidate ops anywhere).
__device__ __forceinline__ void cbar(unsigned* ctr, unsigned& tgt){
  __syncthreads();
  if (threadIdx.x == 0){
    asm volatile("s_waitcnt vmcnt(0)" ::: "memory");
    __hip_atomic_fetch_add(ctr, 1u, __ATOMIC_RELAXED, __HIP_MEMORY_SCOPE_AGENT);
    while (__hip_atomic_load(ctr, __ATOMIC_RELAXED, __HIP_MEMORY_SCOPE_AGENT) < tgt)
      __builtin_amdgcn_s_sleep(2);
  }
  __syncthreads();
  tgt += 16;
}

__global__ __launch_bounds__(BT) void decoder_kernel(Pr P){
  const int blk = blockIdx.x, tid = threadIdx.x;
  const int sq = blk & 15, coh = blk >> 4;      // blk%8 = sq%8 -> slice pinned per XCD
  const int b0 = coh * 4;                       // batches b0..b0+3
  unsigned* ctr = P.ctr + coh*64;

  __shared__ float4 hj4[512];                   // h_att packed [j]{g0..g3}
  __shared__ float4 pj4[80];
  __shared__ float4 h1j4[80];
  __shared__ float4 h2j4[80];
  __shared__ float4 ctx4[32];                   // own 32-e slice
  __shared__ float4 qs4[32];                    // own 32-col q slice
  __shared__ float  c1s[4][80], c2s[4][80];
  __shared__ float  aw[4][1024];
  __shared__ float4 scr4[2048];
  __shared__ float  red2[512];
  __shared__ float  gts[1280];
  __shared__ float  pv[4][16], msta[4][8], mscl[4][8], mwt[4][8];
  __shared__ int    wlo[4], whi[4];

  float* hjF  = (float*)hj4;
  float* pjF  = (float*)pj4;
  float* h1F  = (float*)h1j4;
  float* h2F  = (float*)h2j4;
  float* scrF = (float*)scr4;
  float* qsF  = (float*)qs4;
  float* ctxF = (float*)ctx4;

  { float4 z = {0,0,0,0};
    for (int i=tid;i<512;i+=BT) hj4[i]=z;
    if (tid<80){ pj4[tid]=z; h1j4[tid]=z; h2j4[tid]=z; }
    if (tid<320){ c1s[tid&3][tid>>2]=0.f; c2s[tid&3][tid>>2]=0.f; }
    if (tid<32) msta[tid>>3][tid&7]=0.f;
  }
  __syncthreads();

  unsigned tgt = 16;

  for (int l=0; l<LL; ++l){
    // ===== P0: prenet (redundant) =====
    if (tid<320){
      const int col=tid>>2, g=tid&3;
      float s=P.pb1[col];
      #pragma unroll 4
      for (int j=0;j<80;++j) s += h2F[j*4+g]*P.pW1[j*80+col];
      scrF[col*4+g]=fmaxf(s,0.f);
    }
    __syncthreads();
    if (tid<320){
      const int col=tid>>2, g=tid&3;
      float s=P.pb2[col];
      #pragma unroll 4
      for (int j=0;j<80;++j) s += scrF[j*4+g]*P.pW2[j*80+col];
      pjF[col*4+g]=fmaxf(s,0.f);
    }
    __syncthreads();

    // ===== P1: GRU slice (32 units), 16-way j-split =====
    {
      const int u = tid & 31, jsl = tid >> 5;   // 16 j-slices x 37 rows (592 = 80p + 512h)
      const int cb = sq*32 + u;
      float4 ar={0,0,0,0}, az=ar, axn=ar, ahn=ar;
      const int j0 = jsl*37;
      #pragma unroll 4
      for (int jj=0;jj<37;++jj){
        const int j = j0+jj;
        if (j < 80){
          float4 x = pj4[j];
          const float* W = P.gWx + (size_t)j*1536 + cb;
          acc4(ar,W[0],x); acc4(az,W[512],x); acc4(axn,W[1024],x);
        } else {
          float4 x = hj4[j-80];
          const float* W = P.gWh + (size_t)(j-80)*1536 + cb;
          acc4(ar,W[0],x); acc4(az,W[512],x); acc4(ahn,W[1024],x);
        }
      }
      const int base = jsl*128 + u*4;
      scr4[base+0]=ar; scr4[base+1]=az; scr4[base+2]=axn; scr4[base+3]=ahn;
    }
    __syncthreads();
    {
      float s=0.f;
      #pragma unroll
      for (int k=0;k<16;++k) s += scrF[k*512 + tid];
      red2[tid]=s;                              // [u][gate][g]
    }
    __syncthreads();
    if (tid<128){
      const int u=tid>>2, g=tid&3, uu=sq*32+u;
      float rx=red2[u*16+0+g], zx=red2[u*16+4+g];
      float xn=red2[u*16+8+g], hn=red2[u*16+12+g];
      float r = sigm(rx + P.gbx[uu] + P.gbh[uu]);
      float z = sigm(zx + P.gbx[512+uu] + P.gbh[512+uu]);
      float n = tanhf(xn + P.gbx[1024+uu] + r*(hn + P.gbh[1024+uu]));
      float ho = (1.f-z)*n + z*hjF[uu*4+g];
      gstore(&P.hb[(size_t)(b0+g)*512 + uu], ho);
    }
    cbar(ctr, tgt);                             // ---- barrier A: hout
    {
      float4 h;
      h.x=gload(&P.hb[(size_t)(b0+0)*512+tid]);
      h.y=gload(&P.hb[(size_t)(b0+1)*512+tid]);
      h.z=gload(&P.hb[(size_t)(b0+2)*512+tid]);
      h.w=gload(&P.hb[(size_t)(b0+3)*512+tid]);
      hj4[tid]=h;
    }
    __syncthreads();

    // ===== P2: q slice (32 cols) + param partials =====
    {
      const int c = tid & 31, jsl = tid >> 5;
      const int j0 = jsl*32;
      float4 a={0,0,0,0};
      const float* W = P.aW1 + (size_t)j0*512 + sq*32 + c;
      #pragma unroll 4
      for (int jj=0;jj<32;++jj) acc4(a, W[(size_t)jj*512], hj4[j0+jj]);
      scr4[jsl*32+c]=a;
    }
    __syncthreads();
    if (tid<128){
      const int c=tid>>2, g=tid&3;
      float s=0.f;
      #pragma unroll
      for (int k=0;k<16;++k) s += scrF[k*128 + c*4 + g];
      qsF[c*4+g] = tanhf(s + P.ab1[sq*32+c]);
    }
    __syncthreads();
    if (tid<60){
      const int col=tid%15, g=tid/15;
      float s=0.f;
      #pragma unroll 4
      for (int j=0;j<32;++j) s += qsF[j*4+g]*P.aW2[(size_t)(sq*32+j)*15 + col];
      gstore(&P.pp[(size_t)(b0+g)*256 + sq*16 + col], s);
    }
    cbar(ctr, tgt);                             // ---- barrier B: param partials
    if (tid<60){
      const int col=tid%15, g=tid/15;
      float s=P.ab2[col];
      #pragma unroll
      for (int k=0;k<16;++k) s += gload(&P.pp[(size_t)(b0+g)*256 + k*16 + col]);
      pv[g][col]=s;
    }
    __syncthreads();
    if (tid<4){
      const int g=tid;
      float lo=3.4e38f, hi=-3.4e38f, mmax=-3.4e38f;
      #pragma unroll
      for (int k=0;k<KK;++k){
        float m = msta[g][k] + softplusf(pv[g][k]);
        msta[g][k]=m;
        float sc = softplusf(pv[g][5+k]) + 1e-4f;
        mscl[g][k]=sc;
        mmax = fmaxf(mmax, pv[g][10+k]);
        lo = fminf(lo, m-0.5f-26.f*sc);         // e^-26 tail: mass < 1e-11
        hi = fmaxf(hi, m+0.5f+26.f*sc);
      }
      float den=0.f;
      #pragma unroll
      for (int k=0;k<KK;++k){ float e=expf(pv[g][10+k]-mmax); mwt[g][k]=e; den+=e; }
      float rd=1.f/den;
      #pragma unroll
      for (int k=0;k<KK;++k) mwt[g][k]*=rd;
      int ilo=(int)fmaxf(0.f,floorf(lo));
      int ihi=(int)fminf((float)TT,ceilf(hi)+1.f);
      if (ihi<ilo) ihi=ilo;
      wlo[g]=ilo; whi[g]=ihi;
    }
    __syncthreads();

    // ===== P3: attention weights + ctx slice (32 e) =====
    {
      const int g = tid&3, tl = tid>>2;
      for (int t = wlo[g]+tl; t < whi[g]; t += 128){
        float s=0.f; const float tf=(float)t;
        #pragma unroll
        for (int k=0;k<KK;++k){
          float mu=msta[g][k], sc=mscl[g][k];
          s += mwt[g][k]*(sigm((tf+0.5f-mu)/sc)-sigm((tf-0.5f-mu)/sc));
        }
        aw[g][t]=s;
      }
    }
    __syncthreads();
    {
      const int eq = tid&7, g = (tid>>3)&3, ts = tid>>5;
      const float* bz = P.enc + (size_t)(b0+g)*TT*EE + sq*32 + eq*4;
      float4 acc={0,0,0,0};
      for (int t = wlo[g]+ts; t < whi[g]; t += 16)
        acc4(acc, aw[g][t], *(const float4*)(bz+(size_t)t*EE));
      scr4[ts*32 + g*8 + eq]=acc;
    }
    __syncthreads();
    if (tid<128){
      const int g=tid>>5, e=tid&31;
      float s=0.f;
      #pragma unroll
      for (int k=0;k<16;++k) s += scrF[k*128 + g*32 + e];
      ctxF[e*4+g]=s;
    }
    __syncthreads();

    // ===== P4: LSTM1 partials (69-row j-slice) =====
    if (tid<320){
      const int col=tid;
      float4 a={0,0,0,0};
      { const float* W = P.lWx1 + (size_t)(sq*32)*320 + col;
        #pragma unroll 4
        for (int j=0;j<32;++j) acc4(a, W[(size_t)j*320], ctx4[j]); }
      { const float* W = P.lWx1 + (size_t)(512+sq*32)*320 + col;
        #pragma unroll 4
        for (int j=0;j<32;++j) acc4(a, W[(size_t)j*320], hj4[sq*32+j]); }
      { const float* W = P.lWh1 + (size_t)(sq*5)*320 + col;
        #pragma unroll
        for (int j=0;j<5;++j)  acc4(a, W[(size_t)j*320], h1j4[sq*5+j]); }
      gstore(&P.pl1[(size_t)(b0+0)*5120 + sq*320 + col], a.x);
      gstore(&P.pl1[(size_t)(b0+1)*5120 + sq*320 + col], a.y);
      gstore(&P.pl1[(size_t)(b0+2)*5120 + sq*320 + col], a.z);
      gstore(&P.pl1[(size_t)(b0+3)*5120 + sq*320 + col], a.w);
    }
    cbar(ctr, tgt);                             // ---- barrier C: lstm1 partials
    for (int slot=tid; slot<1280; slot+=BT){
      const int col=slot>>2, g=slot&3;
      float s=P.lb1[col];
      #pragma unroll
      for (int k=0;k<16;++k) s += gload(&P.pl1[(size_t)(b0+g)*5120 + k*320 + col]);
      gts[slot]=s;
    }
    __syncthreads();
    if (tid<320){
      const int u=tid>>2, g=tid&3;
      float i_=sigm(gts[u*4+g]);
      float f_=sigm(gts[(80+u)*4+g]);
      float gg=tanhf(gts[(160+u)*4+g]);
      float o_=sigm(gts[(240+u)*4+g]);
      float cn=f_*c1s[g][u]+i_*gg;
      c1s[g][u]=cn;
      h1F[u*4+g]=o_*tanhf(cn);
    }
    __syncthreads();

    // ===== P5: LSTM2 (redundant) + outputs =====
    if (tid<320){
      const int col=tid;
      float4 a={0,0,0,0};
      { const float* W=P.lWx2+col;
        #pragma unroll 4
        for (int j=0;j<80;++j) acc4(a, W[(size_t)j*320], h1j4[j]); }
      { const float* W=P.lWh2+col;
        #pragma unroll 4
        for (int j=0;j<80;++j) acc4(a, W[(size_t)j*320], h2j4[j]); }
      const float bb=P.lb2[col];
      gts[col*4+0]=a.x+bb; gts[col*4+1]=a.y+bb;
      gts[col*4+2]=a.z+bb; gts[col*4+3]=a.w+bb;
    }
    __syncthreads();
    if (tid<320){
      const int u=tid>>2, g=tid&3;
      float i_=sigm(gts[u*4+g]);
      float f_=sigm(gts[(80+u)*4+g]);
      float gg=tanhf(gts[(160+u)*4+g]);
      float o_=sigm(gts[(240+u)*4+g]);
      float cn=f_*c2s[g][u]+i_*gg;
      c2s[g][u]=cn;
      float hn=o_*tanhf(cn);
      h2F[u*4+g]=hn;
      red2[u*4+g]=hn*P.sW[u];
      if (sq==0){
        const size_t o=((size_t)(b0+g)*LL+l)*DD+u;
        P.oa[o]=hn; P.obf[o]=hn;
      }
    }
    __syncthreads();
    if (tid<4 && sq==0){
      float s=P.sb[0];
      for (int u=0;u<80;++u) s+=red2[u*4+tid];
      P.ol[(size_t)(b0+tid)*LL+l]=s;
    }
    __syncthreads();
  }
}

extern "C" void kernel_launch(void* const* d_in, const int* in_sizes, int n_in,
                              void* d_out, int out_size, void* d_ws, size_t ws_size,
                              hipStream_t stream){
  (void)in_sizes; (void)n_in; (void)out_size;
  if (ws_size < (size_t)WF_TOTAL*sizeof(float)) return;

  hipMemsetAsync(d_ws, 0, 4096, stream);   // zero cohort barrier counters

  Pr P;
  P.enc = (const float*)d_in[0];
  P.pW1=(const float*)d_in[2];  P.pb1=(const float*)d_in[3];
  P.pW2=(const float*)d_in[4];  P.pb2=(const float*)d_in[5];
  P.gWx=(const float*)d_in[6];  P.gWh=(const float*)d_in[7];
  P.gbx=(const float*)d_in[8];  P.gbh=(const float*)d_in[9];
  P.aW1=(const float*)d_in[10]; P.ab1=(const float*)d_in[11];
  P.aW2=(const float*)d_in[12]; P.ab2=(const float*)d_in[13];
  P.lWx1=(const float*)d_in[14]; P.lWh1=(const float*)d_in[15]; P.lb1=(const float*)d_in[16];
  P.lWx2=(const float*)d_in[17]; P.lWh2=(const float*)d_in[18]; P.lb2=(const float*)d_in[19];
  P.sW=(const float*)d_in[20];  P.sb=(const float*)d_in[21];

  float* ws = (float*)d_ws;
  P.ctr = (unsigned*)ws;           // [0..1024) u32
  P.hb  = ws + WF_HB;              // [64][512]
  P.pp  = ws + WF_PP;              // [64][16][16]
  P.pl1 = ws + WF_PL1;             // [64][16][320]

  float* o = (float*)d_out;
  P.oa  = o;
  P.obf = o + (size_t)BB*LL*DD;
  P.ol  = o + (size_t)2*BB*LL*DD;

  void* args[] = { (void*)&P };
  hipLaunchCooperativeKernel((void*)decoder_kernel, dim3(NB), dim3(BT), args, 0, stream);
}

// Round 7
// 15991.251 us; speedup vs baseline: 9.2850x; 1.1023x over previous
//
#include <hip/hip_runtime.h>

#define NB 256      // 16 cohorts x 16 slice-blocks
#define BT 512
#define BB 64
#define TT 1024
#define LL 400
#define EE 512
#define DD 80
#define AA 512
#define KK 5

// ws float offsets
#define WF_HB    1024     // [64][512]  hout exchange
#define WF_PP    33792    // [64][16][16] param partials
#define WF_PL1   50176    // [64][16][320] lstm1 partials
#define WF_TOTAL 377856   // floats

struct Pr {
  const float *enc;
  const float *pW1,*pb1,*pW2,*pb2;
  const float *gWx,*gWh,*gbx,*gbh;
  const float *aW1,*ab1,*aW2,*ab2;
  const float *lWx1,*lWh1,*lb1,*lWx2,*lWh2,*lb2;
  const float *sW,*sb;
  float *oa,*obf,*ol;
  unsigned *ctr;
  float *hb,*pp,*pl1;
};

__device__ __forceinline__ float sigm(float x){ return 1.f/(1.f+expf(-x)); }
__device__ __forceinline__ float softplusf(float x){ return fmaxf(x,0.f)+log1pf(expf(-fabsf(x))); }
__device__ __forceinline__ void gstore(float* p, float v){
  __hip_atomic_store(p, v, __ATOMIC_RELAXED, __HIP_MEMORY_SCOPE_AGENT);
}
__device__ __forceinline__ float gload(const float* p){
  return __hip_atomic_load(p, __ATOMIC_RELAXED, __HIP_MEMORY_SCOPE_AGENT);
}
__device__ __forceinline__ void acc4(float4& a, float w, const float4 x){
  a.x = fmaf(w,x.x,a.x); a.y = fmaf(w,x.y,a.y);
  a.z = fmaf(w,x.z,a.z); a.w = fmaf(w,x.w,a.w);
}

// 16-block cohort barrier — fence-free (proven round 5/6 structure).
__device__ __forceinline__ void cbar(unsigned* ctr, unsigned& tgt){
  __syncthreads();
  if (threadIdx.x == 0){
    asm volatile("s_waitcnt vmcnt(0)" ::: "memory");
    __hip_atomic_fetch_add(ctr, 1u, __ATOMIC_RELAXED, __HIP_MEMORY_SCOPE_AGENT);
    while (__hip_atomic_load(ctr, __ATOMIC_RELAXED, __HIP_MEMORY_SCOPE_AGENT) < tgt)
      __builtin_amdgcn_s_sleep(2);
  }
  __syncthreads();
  tgt += 16;
}

// prenet: p = relu(relu(h2@pW1+b1)@pW2+b2); caller syncs after.
__device__ __forceinline__ void prenet_pass(const Pr& P, const float* h2F,
                                            float* tmp, float* pjF, int tid){
  if (tid<320){
    const int col=tid>>2, g=tid&3;
    float s=P.pb1[col];
    #pragma unroll 4
    for (int j=0;j<80;++j) s = fmaf(h2F[j*4+g], P.pW1[j*80+col], s);
    tmp[col*4+g]=fmaxf(s,0.f);
  }
  __syncthreads();
  if (tid<320){
    const int col=tid>>2, g=tid&3;
    float s=P.pb2[col];
    #pragma unroll 4
    for (int j=0;j<80;++j) s = fmaf(tmp[j*4+g], P.pW2[j*80+col], s);
    pjF[col*4+g]=fmaxf(s,0.f);
  }
}

__global__ __launch_bounds__(BT) void decoder_kernel(Pr P){
  const int blk = blockIdx.x, tid = threadIdx.x;
  const int sq = blk & 15, coh = blk >> 4;     // blk%8 = sq%8 -> slice pinned per XCD
  const int b0 = coh * 4;
  unsigned* ctr = P.ctr + coh*64;

  __shared__ float4 hj4[512];
  __shared__ float4 pj4[80];
  __shared__ float4 h1j4[80];
  __shared__ float4 h2j4[80];
  __shared__ float4 ctx4[32];
  __shared__ float4 qs4[32];
  __shared__ float4 red4[128];
  __shared__ float4 scr4[3700];     // pad >80KB total LDS: force 1 block/CU
  __shared__ float  c1s[4][80], c2s[4][80];
  __shared__ float  gts[1280];
  __shared__ float  pv[4][16], msta[4][8], mscl[4][8], mwt[4][8];
  __shared__ int    wlo[4], whi[4];

  float* hjF=(float*)hj4;  float* pjF=(float*)pj4;  float* h1F=(float*)h1j4;
  float* h2F=(float*)h2j4; float* scrF=(float*)scr4; float* qsF=(float*)qs4;
  float* ctxF=(float*)ctx4; float* redF=(float*)red4;

  { float4 z={0,0,0,0};
    for (int i=tid;i<512;i+=BT) hj4[i]=z;
    if (tid<80){ pj4[tid]=z; h1j4[tid]=z; h2j4[tid]=z; }
    if (tid<320){ c1s[tid&3][tid>>2]=0.f; c2s[tid&3][tid>>2]=0.f; }
    if (tid<32) msta[tid>>3][tid&7]=0.f;
  }
  __syncthreads();

  unsigned tgt = 16;

  for (int l=0; l<LL; ++l){
    // ===== P0: prenet (uses h2 of step l-1) =====
    prenet_pass(P, h2F, gts, pjF, tid);
    __syncthreads();

    // ===== P1: GRU slice (32 units), 16-way j-split =====
    {
      const int u = tid & 31, jsl = tid >> 5;
      const int cb = sq*32 + u;
      float4 ar={0,0,0,0}, az=ar, axn=ar, ahn=ar;
      const int j0 = jsl*37;
      #pragma unroll 4
      for (int jj=0;jj<37;++jj){
        const int j = j0+jj;
        if (j < 80){
          float4 x = pj4[j];
          const float* W = P.gWx + (size_t)j*1536 + cb;
          acc4(ar,W[0],x); acc4(az,W[512],x); acc4(axn,W[1024],x);
        } else {
          float4 x = hj4[j-80];
          const float* W = P.gWh + (size_t)(j-80)*1536 + cb;
          acc4(ar,W[0],x); acc4(az,W[512],x); acc4(ahn,W[1024],x);
        }
      }
      const int base = (jsl*32+u)*4;
      scr4[base+0]=ar; scr4[base+1]=az; scr4[base+2]=axn; scr4[base+3]=ahn;
    }
    __syncthreads();
    if (tid<128){                       // single-stage 16-way reduce
      float4 s={0,0,0,0};
      #pragma unroll
      for (int k=0;k<16;++k){
        float4 v = scr4[k*128+tid];
        s.x+=v.x; s.y+=v.y; s.z+=v.z; s.w+=v.w;
      }
      red4[tid]=s;
    }
    __syncthreads();
    if (tid<128){                       // finish + publish hout slice
      const int u=tid>>2, g=tid&3, uu=sq*32+u;
      float rx=redF[(u*4+0)*4+g], zx=redF[(u*4+1)*4+g];
      float xn=redF[(u*4+2)*4+g], hn=redF[(u*4+3)*4+g];
      float r = sigm(rx + P.gbx[uu] + P.gbh[uu]);
      float z = sigm(zx + P.gbx[512+uu] + P.gbh[512+uu]);
      float n = tanhf(xn + P.gbx[1024+uu] + r*(hn + P.gbh[1024+uu]));
      float ho = (1.f-z)*n + z*hjF[uu*4+g];
      gstore(&P.hb[(size_t)(b0+g)*512 + uu], ho);
    }
    cbar(ctr, tgt);                     // ---- barrier A: hout
    {
      float4 h;
      h.x=gload(&P.hb[(size_t)(b0+0)*512+tid]);
      h.y=gload(&P.hb[(size_t)(b0+1)*512+tid]);
      h.z=gload(&P.hb[(size_t)(b0+2)*512+tid]);
      h.w=gload(&P.hb[(size_t)(b0+3)*512+tid]);
      hj4[tid]=h;
    }
    __syncthreads();

    // ===== P2: q slice (32 cols) + param partials =====
    {
      const int c = tid & 31, jsl = tid >> 5, j0 = jsl*32;
      float4 a={0,0,0,0};
      const float* W = P.aW1 + (size_t)j0*512 + sq*32 + c;
      #pragma unroll 4
      for (int jj=0;jj<32;++jj) acc4(a, W[(size_t)jj*512], hj4[j0+jj]);
      scr4[jsl*32+c]=a;
    }
    __syncthreads();
    if (tid<128){
      const int c=tid>>2, g=tid&3;
      float s=0.f;
      #pragma unroll
      for (int k=0;k<16;++k) s += scrF[(k*32+c)*4+g];
      qsF[c*4+g] = tanhf(s + P.ab1[sq*32+c]);
    }
    __syncthreads();
    if (tid<60){
      const int col=tid%15, g=tid/15;
      float s=0.f;
      #pragma unroll 4
      for (int j=0;j<32;++j) s = fmaf(qsF[j*4+g], P.aW2[(size_t)(sq*32+j)*15+col], s);
      gstore(&P.pp[(size_t)(b0+g)*256 + sq*16 + col], s);
    }
    // ---- B-shadow: LSTM1 h-part + h1-part into registers ----
    float4 l1acc={0,0,0,0};
    if (tid<320){
      { const float* W = P.lWx1 + (size_t)(512+sq*32)*320 + tid;
        #pragma unroll 4
        for (int j=0;j<32;++j) acc4(l1acc, W[(size_t)j*320], hj4[sq*32+j]); }
      { const float* W = P.lWh1 + (size_t)(sq*5)*320 + tid;
        #pragma unroll
        for (int j=0;j<5;++j)  acc4(l1acc, W[(size_t)j*320], h1j4[sq*5+j]); }
    }
    cbar(ctr, tgt);                     // ---- barrier B: param partials
    if (tid<60){
      const int col=tid%15, g=tid/15;
      float s=P.ab2[col];
      #pragma unroll
      for (int k=0;k<16;++k) s += gload(&P.pp[(size_t)(b0+g)*256 + k*16 + col]);
      pv[g][col]=s;
    }
    __syncthreads();
    if (tid<4){
      const int g=tid;
      float lo=3.4e38f, hi=-3.4e38f, mmax=-3.4e38f;
      #pragma unroll
      for (int k=0;k<KK;++k){
        float m = msta[g][k] + softplusf(pv[g][k]);
        msta[g][k]=m;
        float sc = softplusf(pv[g][5+k]) + 1e-4f;
        mscl[g][k]=sc;
        mmax = fmaxf(mmax, pv[g][10+k]);
        lo = fminf(lo, m-0.5f-26.f*sc);  // e^-26 tail: mass < 1e-11
        hi = fmaxf(hi, m+0.5f+26.f*sc);
      }
      float den=0.f;
      #pragma unroll
      for (int k=0;k<KK;++k){ float e=expf(pv[g][10+k]-mmax); mwt[g][k]=e; den+=e; }
      float rd=1.f/den;
      #pragma unroll
      for (int k=0;k<KK;++k) mwt[g][k]*=rd;
      int ilo=(int)fmaxf(0.f,floorf(lo));
      int ihi=(int)fminf((float)TT,ceilf(hi)+1.f);
      if (ihi<ilo) ihi=ilo;
      wlo[g]=ilo; whi[g]=ihi;
    }
    __syncthreads();

    // ===== P3: ctx slice (32 e), aw inlined per-lane =====
    {
      const int eq = tid&7, g = (tid>>3)&3, ts = tid>>5;
      const float* bz = P.enc + (size_t)(b0+g)*TT*EE + sq*32 + eq*4;
      float4 acc={0,0,0,0};
      for (int t = wlo[g]+ts; t < whi[g]; t += 16){
        const float tf=(float)t;
        float awv=0.f;
        #pragma unroll
        for (int k=0;k<KK;++k){
          float mu=msta[g][k], sc=mscl[g][k];
          awv += mwt[g][k]*(sigm((tf+0.5f-mu)/sc)-sigm((tf-0.5f-mu)/sc));
        }
        acc4(acc, awv, *(const float4*)(bz+(size_t)t*EE));
      }
      scr4[ts*32 + g*8 + eq]=acc;
    }
    __syncthreads();
    if (tid<128){
      const int g=tid>>5, e=tid&31;
      float s=0.f;
      #pragma unroll
      for (int k=0;k<16;++k) s += scrF[(k*32 + g*8 + (e>>2))*4 + (e&3)];
      ctxF[e*4+g]=s;
    }
    __syncthreads();

    // ===== P4: ctx-part + publish LSTM1 partials =====
    if (tid<320){
      const float* W = P.lWx1 + (size_t)(sq*32)*320 + tid;
      #pragma unroll 4
      for (int j=0;j<32;++j) acc4(l1acc, W[(size_t)j*320], ctx4[j]);
      gstore(&P.pl1[(size_t)(b0+0)*5120 + sq*320 + tid], l1acc.x);
      gstore(&P.pl1[(size_t)(b0+1)*5120 + sq*320 + tid], l1acc.y);
      gstore(&P.pl1[(size_t)(b0+2)*5120 + sq*320 + tid], l1acc.z);
      gstore(&P.pl1[(size_t)(b0+3)*5120 + sq*320 + tid], l1acc.w);
    }
    // ---- C-shadow: LSTM2 h2-part (h2 is step l-1 state) ----
    if (tid<320){
      float4 a={0,0,0,0};
      const float* W = P.lWh2 + tid;
      #pragma unroll 4
      for (int j=0;j<80;++j) acc4(a, W[(size_t)j*320], h2j4[j]);
      scr4[1024+tid]=a;
    }
    cbar(ctr, tgt);                     // ---- barrier C: lstm1 partials
    for (int slot=tid; slot<1280; slot+=BT){
      const int col=slot>>2, g=slot&3;
      float s=P.lb1[col];
      #pragma unroll
      for (int k=0;k<16;++k) s += gload(&P.pl1[(size_t)(b0+g)*5120 + k*320 + col]);
      gts[slot]=s;
    }
    __syncthreads();
    if (tid<320){                       // h1/c1 update
      const int u=tid>>2, g=tid&3;
      float i_=sigm(gts[u*4+g]);
      float f_=sigm(gts[(80+u)*4+g]);
      float g_=tanhf(gts[(160+u)*4+g]);
      float o_=sigm(gts[(240+u)*4+g]);
      float cn=f_*c1s[g][u]+i_*g_;
      c1s[g][u]=cn;
      h1F[u*4+g]=o_*tanhf(cn);
    }
    __syncthreads();
    if (tid<320){                       // LSTM2 h1-part + gates
      float4 a = scr4[1024+tid];
      const float* W = P.lWx2 + tid;
      #pragma unroll 4
      for (int j=0;j<80;++j) acc4(a, W[(size_t)j*320], h1j4[j]);
      const float bb=P.lb2[tid];
      a.x+=bb; a.y+=bb; a.z+=bb; a.w+=bb;
      scr4[1024+tid]=a;
    }
    __syncthreads();
    if (tid<320){                       // c2/h2 update + outputs
      const int u=tid>>2, g=tid&3;
      float i_=sigm(scrF[(1024+u)*4+g]);
      float f_=sigm(scrF[(1104+u)*4+g]);
      float g_=tanhf(scrF[(1184+u)*4+g]);
      float o_=sigm(scrF[(1264+u)*4+g]);
      float cn=f_*c2s[g][u]+i_*g_;
      c2s[g][u]=cn;
      float hn=o_*tanhf(cn);
      h2F[u*4+g]=hn;
      redF[u*4+g]=hn*P.sW[u];
      if (sq==0){
        const size_t o=((size_t)(b0+g)*LL+l)*DD+u;
        P.oa[o]=hn; P.obf[o]=hn;
      }
    }
    __syncthreads();
    if (tid<4 && sq==0){                // stop logit (overlaps next P0)
      float s=P.sb[0];
      for (int u=0;u<80;++u) s+=redF[u*4+tid];
      P.ol[(size_t)(b0+tid)*LL+l]=s;
    }
  }
}

extern "C" void kernel_launch(void* const* d_in, const int* in_sizes, int n_in,
                              void* d_out, int out_size, void* d_ws, size_t ws_size,
                              hipStream_t stream){
  (void)in_sizes; (void)n_in; (void)out_size;
  if (ws_size < (size_t)WF_TOTAL*sizeof(float)) return;

  hipMemsetAsync(d_ws, 0, 4096, stream);   // zero cohort barrier counters

  Pr P;
  P.enc = (const float*)d_in[0];
  P.pW1=(const float*)d_in[2];  P.pb1=(const float*)d_in[3];
  P.pW2=(const float*)d_in[4];  P.pb2=(const float*)d_in[5];
  P.gWx=(const float*)d_in[6];  P.gWh=(const float*)d_in[7];
  P.gbx=(const float*)d_in[8];  P.gbh=(const float*)d_in[9];
  P.aW1=(const float*)d_in[10]; P.ab1=(const float*)d_in[11];
  P.aW2=(const float*)d_in[12]; P.ab2=(const float*)d_in[13];
  P.lWx1=(const float*)d_in[14]; P.lWh1=(const float*)d_in[15]; P.lb1=(const float*)d_in[16];
  P.lWx2=(const float*)d_in[17]; P.lWh2=(const float*)d_in[18]; P.lb2=(const float*)d_in[19];
  P.sW=(const float*)d_in[20];  P.sb=(const float*)d_in[21];

  float* ws = (float*)d_ws;
  P.ctr = (unsigned*)ws;
  P.hb  = ws + WF_HB;
  P.pp  = ws + WF_PP;
  P.pl1 = ws + WF_PL1;

  float* o = (float*)d_out;
  P.oa  = o;
  P.obf = o + (size_t)BB*LL*DD;
  P.ol  = o + (size_t)2*BB*LL*DD;

  void* args[] = { (void*)&P };
  hipLaunchCooperativeKernel((void*)decoder_kernel, dim3(NB), dim3(BT), args, 0, stream);
}

// Round 8
// 14320.627 us; speedup vs baseline: 10.3682x; 1.1167x over previous
//
#include <hip/hip_runtime.h>

#define NB 256      // 16 cohorts x 16 slice-blocks
#define BT 512
#define BB 64
#define TT 1024
#define LL 400
#define EE 512
#define DD 80
#define AA 512
#define KK 5

// ws float offsets
#define WF_HB    1024                 // [64][512] hout exchange
#define WF_PP    33792                // [64][16][16] param partials
#define WF_PL1   50176                // [64][16][320] lstm1 partials
#define WF_EW    377856               // [64][1024][320] enc@Wx1 (optional)
#define WF_EWSZ  (64UL*1024UL*320UL)

struct Pr {
  const float *enc;
  const float *pW1,*pb1,*pW2,*pb2;
  const float *gWx,*gWh,*gbx,*gbh;
  const float *aW1,*ab1,*aW2,*ab2;
  const float *lWx1,*lWh1,*lb1,*lWx2,*lWh2,*lb2;
  const float *sW,*sb;
  float *oa,*obf,*ol;
  unsigned *ctr;
  float *hb,*pp,*pl1,*ew;
  int useEW;
};

__device__ __forceinline__ float sigm(float x){ return 1.f/(1.f+expf(-x)); }
__device__ __forceinline__ float softplusf(float x){ return fmaxf(x,0.f)+log1pf(expf(-fabsf(x))); }
__device__ __forceinline__ void gstore(float* p, float v){
  __hip_atomic_store(p, v, __ATOMIC_RELAXED, __HIP_MEMORY_SCOPE_AGENT);
}
__device__ __forceinline__ float gload(const float* p){
  return __hip_atomic_load(p, __ATOMIC_RELAXED, __HIP_MEMORY_SCOPE_AGENT);
}
__device__ __forceinline__ void acc4(float4& a, float w, const float4 x){
  a.x = fmaf(w,x.x,a.x); a.y = fmaf(w,x.y,a.y);
  a.z = fmaf(w,x.z,a.z); a.w = fmaf(w,x.w,a.w);
}

// split cohort barrier (16 blocks): arrive ASAP, wait later; RTT hides under shadow
__device__ __forceinline__ void cbar_arrive(unsigned* ctr){
  __syncthreads();                     // all waves' agent stores drained (vmcnt0 per wave)
  if (threadIdx.x == 0){
    asm volatile("s_waitcnt vmcnt(0)" ::: "memory");
    __hip_atomic_fetch_add(ctr, 1u, __ATOMIC_RELAXED, __HIP_MEMORY_SCOPE_AGENT);
  }
}
__device__ __forceinline__ void cbar_wait(unsigned* ctr, unsigned& tgt){
  if (threadIdx.x == 0){
    while (__hip_atomic_load(ctr, __ATOMIC_RELAXED, __HIP_MEMORY_SCOPE_AGENT) < tgt)
      __builtin_amdgcn_s_sleep(1);
  }
  __syncthreads();
  tgt += 16;
}

// one-time EW[b][t][col] = sum_e enc[b][t][e] * lWx1[e][col]  (rows 0..511)
__global__ __launch_bounds__(512) void ew_kernel(const float* __restrict__ enc,
                                                 const float* __restrict__ W,
                                                 float* __restrict__ EW){
  const int b = blockIdx.x, t0 = blockIdx.y*16, tid = threadIdx.x;
  __shared__ float encT[512*16];       // [e][t] stride 16 (64B rows, b128-aligned)
  #pragma unroll
  for (int r=0;r<16;++r)
    encT[tid*16+r] = enc[((size_t)b*TT + t0 + r)*EE + tid];
  __syncthreads();
  if (tid < 320){
    float acc[16];
    #pragma unroll
    for (int k=0;k<16;++k) acc[k]=0.f;
    const float* wp = W + tid;
    #pragma unroll 2
    for (int e=0;e<512;++e){
      float w = wp[(size_t)e*320];
      const float4* er = (const float4*)&encT[e*16];
      float4 x0=er[0], x1=er[1], x2=er[2], x3=er[3];
      acc[0]=fmaf(w,x0.x,acc[0]); acc[1]=fmaf(w,x0.y,acc[1]);
      acc[2]=fmaf(w,x0.z,acc[2]); acc[3]=fmaf(w,x0.w,acc[3]);
      acc[4]=fmaf(w,x1.x,acc[4]); acc[5]=fmaf(w,x1.y,acc[5]);
      acc[6]=fmaf(w,x1.z,acc[6]); acc[7]=fmaf(w,x1.w,acc[7]);
      acc[8]=fmaf(w,x2.x,acc[8]); acc[9]=fmaf(w,x2.y,acc[9]);
      acc[10]=fmaf(w,x2.z,acc[10]); acc[11]=fmaf(w,x2.w,acc[11]);
      acc[12]=fmaf(w,x3.x,acc[12]); acc[13]=fmaf(w,x3.y,acc[13]);
      acc[14]=fmaf(w,x3.z,acc[14]); acc[15]=fmaf(w,x3.w,acc[15]);
    }
    #pragma unroll
    for (int k=0;k<16;++k)
      EW[((size_t)b*TT + t0 + k)*320 + tid] = acc[k];
  }
}

__global__ __launch_bounds__(BT) void decoder_kernel(Pr P){
  const int blk = blockIdx.x, tid = threadIdx.x;
  const int sq = blk & 15, coh = blk >> 4;     // blk%8 = sq%8 -> slice pinned per XCD
  const int b0 = coh * 4;
  unsigned* ctr = P.ctr + coh*64;

  __shared__ float4 hj4[512];
  __shared__ float4 pj4[DD];
  __shared__ float4 h1j4[DD];
  __shared__ float4 h2j4[DD];
  __shared__ float4 qs4[32];
  __shared__ float4 ctx4[32];
  __shared__ float4 red4[128];
  __shared__ float4 scr4[2048];
  __shared__ float4 l2a4[320];
  __shared__ float  gts[1280];
  __shared__ float  stp[320];
  __shared__ float  awb[4][1024];
  __shared__ float  c1s[4][80], c2s[4][80];
  __shared__ float  pv[4][16], msta[4][8], mscl[4][8], mwt[4][8];
  __shared__ int    wlo[4], whi[4];

  float* hjF=(float*)hj4;  float* pjF=(float*)pj4;  float* h1F=(float*)h1j4;
  float* h2F=(float*)h2j4; float* scrF=(float*)scr4; float* qsF=(float*)qs4;
  float* ctxF=(float*)ctx4; float* redF=(float*)red4;

  { float4 z={0,0,0,0};
    for (int i=tid;i<512;i+=BT) hj4[i]=z;
    if (tid<DD){ pj4[tid]=z; h1j4[tid]=z; h2j4[tid]=z; }
    if (tid<320){ c1s[tid&3][tid>>2]=0.f; c2s[tid&3][tid>>2]=0.f; }
    if (tid<32) msta[tid>>3][tid&7]=0.f;
  }
  __syncthreads();

  unsigned tgt = 16;

  for (int l=0; l<LL; ++l){
    // ===== P0: prenet (h2 of step l-1) =====
    if (tid<320){
      const int col=tid>>2, g=tid&3;
      float s=P.pb1[col];
      #pragma unroll 4
      for (int j=0;j<DD;++j) s = fmaf(h2F[j*4+g], P.pW1[j*DD+col], s);
      gts[col*4+g]=fmaxf(s,0.f);
    }
    __syncthreads();
    if (tid<320){
      const int col=tid>>2, g=tid&3;
      float s=P.pb2[col];
      #pragma unroll 4
      for (int j=0;j<DD;++j) s = fmaf(gts[j*4+g], P.pW2[j*DD+col], s);
      pjF[col*4+g]=fmaxf(s,0.f);
    }
    __syncthreads();

    // ===== P1: GRU slice (32 units), 16-way j-split, gate-major scr =====
    {
      const int u = tid & 31, jsl = tid >> 5;
      const int cb = sq*32 + u;
      float4 ar={0,0,0,0}, az=ar, axn=ar, ahn=ar;
      const int j0 = jsl*37;
      #pragma unroll 4
      for (int jj=0;jj<37;++jj){
        const int j = j0+jj;
        if (j < 80){
          float4 x = pj4[j];
          const float* W = P.gWx + (size_t)j*1536 + cb;
          acc4(ar,W[0],x); acc4(az,W[512],x); acc4(axn,W[1024],x);
        } else {
          float4 x = hj4[j-80];
          const float* W = P.gWh + (size_t)(j-80)*1536 + cb;
          acc4(ar,W[0],x); acc4(az,W[512],x); acc4(ahn,W[1024],x);
        }
      }
      scr4[0*512 + jsl*32 + u]=ar;  scr4[1*512 + jsl*32 + u]=az;
      scr4[2*512 + jsl*32 + u]=axn; scr4[3*512 + jsl*32 + u]=ahn;
    }
    __syncthreads();
    if (tid<128){                        // per (gate,u) 16-way reduce
      const int gate=tid>>5, u=tid&31;
      float4 s={0,0,0,0};
      #pragma unroll
      for (int k=0;k<16;++k){
        float4 v = scr4[gate*512 + k*32 + u];
        s.x+=v.x; s.y+=v.y; s.z+=v.z; s.w+=v.w;
      }
      red4[gate*32+u]=s;
    }
    __syncthreads();
    if (tid<128){                        // finish + publish hout slice
      const int u=tid>>2, g=tid&3, uu=sq*32+u;
      float rx=redF[(0*32+u)*4+g], zx=redF[(1*32+u)*4+g];
      float xn=redF[(2*32+u)*4+g], hn=redF[(3*32+u)*4+g];
      float r = sigm(rx + P.gbx[uu] + P.gbh[uu]);
      float z = sigm(zx + P.gbx[512+uu] + P.gbh[512+uu]);
      float n = tanhf(xn + P.gbx[1024+uu] + r*(hn + P.gbh[1024+uu]));
      float ho = (1.f-z)*n + z*hjF[uu*4+g];
      gstore(&P.hb[(size_t)(b0+g)*512 + uu], ho);
    }
    cbar_arrive(ctr);                    // ---- A arrive
    // A-shadow: LSTM2 h2-part (h2 = step l-1)
    if (tid<320){
      float4 a={0,0,0,0};
      const float* W = P.lWh2 + tid;
      #pragma unroll 4
      for (int j=0;j<DD;++j) acc4(a, W[(size_t)j*320], h2j4[j]);
      l2a4[tid]=a;
    }
    cbar_wait(ctr, tgt);                 // ---- A wait
    {
      float4 h;
      h.x=gload(&P.hb[(size_t)(b0+0)*512+tid]);
      h.y=gload(&P.hb[(size_t)(b0+1)*512+tid]);
      h.z=gload(&P.hb[(size_t)(b0+2)*512+tid]);
      h.w=gload(&P.hb[(size_t)(b0+3)*512+tid]);
      hj4[tid]=h;
    }
    __syncthreads();

    // ===== P2: q slice (32 cols) + param partials =====
    {
      const int c = tid & 31, jsl = tid >> 5, j0 = jsl*32;
      float4 a={0,0,0,0};
      const float* W = P.aW1 + (size_t)j0*512 + sq*32 + c;
      #pragma unroll 4
      for (int jj=0;jj<32;++jj) acc4(a, W[(size_t)jj*512], hj4[j0+jj]);
      scr4[jsl*32+c]=a;
    }
    __syncthreads();
    if (tid<128){
      const int c=tid>>2, g=tid&3;
      float s=0.f;
      #pragma unroll
      for (int k=0;k<16;++k) s += scrF[(k*32+c)*4+g];
      qsF[c*4+g] = tanhf(s + P.ab1[sq*32+c]);
    }
    __syncthreads();
    if (tid<60){
      const int col=tid%15, g=tid/15;
      float s=0.f;
      #pragma unroll 4
      for (int j=0;j<32;++j) s = fmaf(qsF[j*4+g], P.aW2[(size_t)(sq*32+j)*15+col], s);
      gstore(&P.pp[(size_t)(b0+g)*256 + sq*16 + col], s);
    }
    cbar_arrive(ctr);                    // ---- B arrive
    // B-shadow: LSTM1 h-part + h1-part into registers
    float4 l1acc={0,0,0,0};
    if (tid<320){
      { const float* W = P.lWx1 + (size_t)(512+sq*32)*320 + tid;
        #pragma unroll 4
        for (int j=0;j<32;++j) acc4(l1acc, W[(size_t)j*320], hj4[sq*32+j]); }
      { const float* W = P.lWh1 + (size_t)(sq*5)*320 + tid;
        #pragma unroll
        for (int j=0;j<5;++j)  acc4(l1acc, W[(size_t)j*320], h1j4[sq*5+j]); }
    }
    cbar_wait(ctr, tgt);                 // ---- B wait
    if (tid<60){
      const int col=tid%15, g=tid/15;
      float s=P.ab2[col];
      #pragma unroll
      for (int k=0;k<16;++k) s += gload(&P.pp[(size_t)(b0+g)*256 + k*16 + col]);
      pv[g][col]=s;
    }
    __syncthreads();
    if (tid<4){
      const int g=tid;
      float lo=3.4e38f, hi=-3.4e38f, mmax=-3.4e38f;
      #pragma unroll
      for (int k=0;k<KK;++k){
        float m = msta[g][k] + softplusf(pv[g][k]);
        msta[g][k]=m;
        float sc = softplusf(pv[g][5+k]) + 1e-4f;
        mscl[g][k]=sc;
        mmax = fmaxf(mmax, pv[g][10+k]);
        lo = fminf(lo, m-0.5f-26.f*sc);  // e^-26 tail: mass < 1e-11
        hi = fmaxf(hi, m+0.5f+26.f*sc);
      }
      float den=0.f;
      #pragma unroll
      for (int k=0;k<KK;++k){ float e=expf(pv[g][10+k]-mmax); mwt[g][k]=e; den+=e; }
      float rd=1.f/den;
      #pragma unroll
      for (int k=0;k<KK;++k) mwt[g][k]*=rd;
      int ilo=(int)fmaxf(0.f,floorf(lo));
      int ihi=(int)fminf((float)TT,ceilf(hi)+1.f);
      if (ihi<ilo) ihi=ilo;
      wlo[g]=ilo; whi[g]=ihi;
    }
    __syncthreads();

    // ===== P3: attention-weighted x-part =====
    if (P.useEW){
      { // stage aw per g into LDS
        const int g = tid>>7, lane = tid&127;
        const int lo_=wlo[g], hi_=whi[g];
        for (int t = lo_+lane; t < hi_; t += 128){
          const float tf=(float)t;
          float s=0.f;
          #pragma unroll
          for (int k=0;k<KK;++k){
            float mu=msta[g][k], sc=mscl[g][k];
            s += mwt[g][k]*(sigm((tf+0.5f-mu)/sc)-sigm((tf-0.5f-mu)/sc));
          }
          awb[g][t-lo_]=s;
        }
      }
      __syncthreads();
      if (tid<320){                      // l1acc += sum_t aw[t]*EW[b][t][col], own t-slice
        const float* EWb = P.ew;
        { const int lo_=wlo[0];
          for (int t=lo_+sq; t<whi[0]; t+=16)
            l1acc.x = fmaf(awb[0][t-lo_], EWb[((size_t)(b0+0)*TT+t)*320+tid], l1acc.x); }
        { const int lo_=wlo[1];
          for (int t=lo_+sq; t<whi[1]; t+=16)
            l1acc.y = fmaf(awb[1][t-lo_], EWb[((size_t)(b0+1)*TT+t)*320+tid], l1acc.y); }
        { const int lo_=wlo[2];
          for (int t=lo_+sq; t<whi[2]; t+=16)
            l1acc.z = fmaf(awb[2][t-lo_], EWb[((size_t)(b0+2)*TT+t)*320+tid], l1acc.z); }
        { const int lo_=wlo[3];
          for (int t=lo_+sq; t<whi[3]; t+=16)
            l1acc.w = fmaf(awb[3][t-lo_], EWb[((size_t)(b0+3)*TT+t)*320+tid], l1acc.w); }
      }
    } else {
      { // ctx slice (32 e), aw inlined per-lane (round-7 path)
        const int eq = tid&7, g = (tid>>3)&3, ts = tid>>5;
        const float* bz = P.enc + (size_t)(b0+g)*TT*EE + sq*32 + eq*4;
        float4 acc={0,0,0,0};
        for (int t = wlo[g]+ts; t < whi[g]; t += 16){
          const float tf=(float)t;
          float awv=0.f;
          #pragma unroll
          for (int k=0;k<KK;++k){
            float mu=msta[g][k], sc=mscl[g][k];
            awv += mwt[g][k]*(sigm((tf+0.5f-mu)/sc)-sigm((tf-0.5f-mu)/sc));
          }
          acc4(acc, awv, *(const float4*)(bz+(size_t)t*EE));
        }
        scr4[ts*32 + g*8 + eq]=acc;
      }
      __syncthreads();
      if (tid<128){
        const int g=tid>>5, e=tid&31;
        float s=0.f;
        #pragma unroll
        for (int k=0;k<16;++k) s += scrF[(k*32 + g*8 + (e>>2))*4 + (e&3)];
        ctxF[e*4+g]=s;
      }
      __syncthreads();
      if (tid<320){
        const float* W = P.lWx1 + (size_t)(sq*32)*320 + tid;
        #pragma unroll 4
        for (int j=0;j<32;++j) acc4(l1acc, W[(size_t)j*320], ctx4[j]);
      }
    }
    if (tid<320){                        // publish LSTM1 partials
      gstore(&P.pl1[(size_t)(b0+0)*5120 + sq*320 + tid], l1acc.x);
      gstore(&P.pl1[(size_t)(b0+1)*5120 + sq*320 + tid], l1acc.y);
      gstore(&P.pl1[(size_t)(b0+2)*5120 + sq*320 + tid], l1acc.z);
      gstore(&P.pl1[(size_t)(b0+3)*5120 + sq*320 + tid], l1acc.w);
    }
    cbar_arrive(ctr);                    // ---- C arrive
    cbar_wait(ctr, tgt);                 // ---- C wait (no shadow available)
    for (int slot=tid; slot<1280; slot+=BT){
      const int col=slot>>2, g=slot&3;
      float s=P.lb1[col];
      #pragma unroll
      for (int k=0;k<16;++k) s += gload(&P.pl1[(size_t)(b0+g)*5120 + k*320 + col]);
      gts[slot]=s;
    }
    __syncthreads();
    if (tid<320){                        // h1/c1 update (redundant, all 80 units)
      const int u=tid>>2, g=tid&3;
      float i_=sigm(gts[u*4+g]);
      float f_=sigm(gts[(80+u)*4+g]);
      float g_=tanhf(gts[(160+u)*4+g]);
      float o_=sigm(gts[(240+u)*4+g]);
      float cn=f_*c1s[g][u]+i_*g_;
      c1s[g][u]=cn;
      h1F[u*4+g]=o_*tanhf(cn);
    }
    __syncthreads();
    if (tid<320){                        // LSTM2 h1-part + gates (h2-part from A-shadow)
      float4 a = l2a4[tid];
      const float* W = P.lWx2 + tid;
      #pragma unroll 4
      for (int j=0;j<DD;++j) acc4(a, W[(size_t)j*320], h1j4[j]);
      const float bb=P.lb2[tid];
      a.x+=bb; a.y+=bb; a.z+=bb; a.w+=bb;
      scr4[tid]=a;
    }
    __syncthreads();
    if (tid<320){                        // c2/h2 update + outputs
      const int u=tid>>2, g=tid&3;
      float i_=sigm(scrF[(0*80+u)*4+g]);
      float f_=sigm(scrF[(1*80+u)*4+g]);
      float g_=tanhf(scrF[(2*80+u)*4+g]);
      float o_=sigm(scrF[(3*80+u)*4+g]);
      float cn=f_*c2s[g][u]+i_*g_;
      c2s[g][u]=cn;
      float hn=o_*tanhf(cn);
      h2F[u*4+g]=hn;
      stp[u*4+g]=hn*P.sW[u];
      if (sq==0){
        const size_t o=((size_t)(b0+g)*LL+l)*DD+u;
        P.oa[o]=hn; P.obf[o]=hn;
      }
    }
    __syncthreads();
    if (tid<4 && sq==0){                 // stop logit (straggles into next P0 safely)
      float s=P.sb[0];
      for (int u=0;u<DD;++u) s+=stp[u*4+tid];
      P.ol[(size_t)(b0+tid)*LL+l]=s;
    }
  }
}

extern "C" void kernel_launch(void* const* d_in, const int* in_sizes, int n_in,
                              void* d_out, int out_size, void* d_ws, size_t ws_size,
                              hipStream_t stream){
  (void)in_sizes; (void)n_in; (void)out_size;
  if (ws_size < (size_t)WF_EW*sizeof(float)) return;   // fallback minimum (round-7 level)
  const int useEW = ws_size >= (size_t)(WF_EW + WF_EWSZ)*sizeof(float);

  hipMemsetAsync(d_ws, 0, 4096, stream);   // zero cohort barrier counters

  Pr P;
  P.enc = (const float*)d_in[0];
  P.pW1=(const float*)d_in[2];  P.pb1=(const float*)d_in[3];
  P.pW2=(const float*)d_in[4];  P.pb2=(const float*)d_in[5];
  P.gWx=(const float*)d_in[6];  P.gWh=(const float*)d_in[7];
  P.gbx=(const float*)d_in[8];  P.gbh=(const float*)d_in[9];
  P.aW1=(const float*)d_in[10]; P.ab1=(const float*)d_in[11];
  P.aW2=(const float*)d_in[12]; P.ab2=(const float*)d_in[13];
  P.lWx1=(const float*)d_in[14]; P.lWh1=(const float*)d_in[15]; P.lb1=(const float*)d_in[16];
  P.lWx2=(const float*)d_in[17]; P.lWh2=(const float*)d_in[18]; P.lb2=(const float*)d_in[19];
  P.sW=(const float*)d_in[20];  P.sb=(const float*)d_in[21];

  float* ws = (float*)d_ws;
  P.ctr = (unsigned*)ws;
  P.hb  = ws + WF_HB;
  P.pp  = ws + WF_PP;
  P.pl1 = ws + WF_PL1;
  P.ew  = ws + WF_EW;
  P.useEW = useEW;

  if (useEW)
    ew_kernel<<<dim3(BB, TT/16), 512, 0, stream>>>(P.enc, P.lWx1, P.ew);

  float* o = (float*)d_out;
  P.oa  = o;
  P.obf = o + (size_t)BB*LL*DD;
  P.ol  = o + (size_t)2*BB*LL*DD;

  void* args[] = { (void*)&P };
  hipLaunchCooperativeKernel((void*)decoder_kernel, dim3(NB), dim3(BT), args, 0, stream);
}